// Round 10
// baseline (416.507 us; speedup 1.0000x reference)
//
#include <hip/hip_runtime.h>
#include <hip/hip_bf16.h>
#include <math.h>

// ---------------------------------------------------------------------------
// KGAT on MI355X.
//   N = 100000 entities, R = 12 relations, D = 64, E = 1e6 edges.
//   proj[k,n,r] = sum_d emb[n,d] * W_r[k,d,r]   -> bf16 MFMA GEMM (PLANE-major)
//   logits[e]   = sum_r proj[et,src,r] * tanh(proj[et,dst,r] + rel[et,r])
//   att         = edge_softmax(logits, by dst)  (unnormalized exp; logits bounded)
//   layer(x):   h = segsum(x[src]*att -> dst); y = lrelu((x+h)W1^T+b1)+lrelu((x*h)W2^T+b2)
//   out = [x0 | x1 | x2]  row stride 160 (f32)
// R17: R16 was flat (406) because bsort1 costs ~30us wherever it lives (123
//     long blocks, 32 serial iters) and projm's 782 blocks = 3.05/CU left the
//     write stream unsaturated (occ 22%, 2.5 TB/s).
//     (a) projm tile 128 -> 64 nodes (4 waves x 16 rows, LDS 9KB): 1563
//         blocks = 6.1/CU all-resident; same FLOP/byte, same 1KB stores.
//     (b) bsort1 tile 8192 -> 2048 (489 blocks, 8 serial iters): 4x more
//         parallelism; staging runs ~10 edges (write amp 8->14MB, cheap).
//     (c) k_bscan DELETED: each bsort2 block scans the <=256-entry bcur in
//         LDS itself (~1us total); one dispatch + dependency removed.
// ---------------------------------------------------------------------------

typedef __attribute__((ext_vector_type(8))) short short8;   // 8 bf16 (4 VGPR)
typedef __attribute__((ext_vector_type(4))) float float4v;  // MFMA acc

__device__ __forceinline__ short f2bf(float f) {
  __hip_bfloat16 h = __float2bfloat16(f);
  return *(short*)&h;
}
__device__ __forceinline__ float bf2f(short s) {
  return __uint_as_float(((unsigned)(unsigned short)s) << 16);
}

#define LOG2E 1.4426950408889634f
#define BS1_TILE 2048

// Merged prep: [0,nb1) bucket-sort pass B (latency-bound, starts at t=0) |
// then emb f32->bf16 | 12 blocks W_r transpose+cvt | 48 blocks layer-weight
// hi/lo bf16 split.
__global__ void k_prep(const float* __restrict__ emb, short* __restrict__ emb_h,
                       const float* __restrict__ Wr, short* __restrict__ Bt,
                       const float* __restrict__ W10, const float* __restrict__ W20,
                       const float* __restrict__ W11, const float* __restrict__ W21,
                       short* __restrict__ w1h0, short* __restrict__ w1l0,
                       short* __restrict__ w2h0, short* __restrict__ w2l0,
                       short* __restrict__ w1h1, short* __restrict__ w1l1,
                       short* __restrict__ w2h1, short* __restrict__ w2l1,
                       const int* __restrict__ src, const int* __restrict__ dst,
                       const int* __restrict__ et, int* __restrict__ bcur,
                       uint2* __restrict__ stg, int nE, int bsh, int cap,
                       int nb1, int nb_cvt, int n4) {
  __shared__ int hist[256];
  __shared__ int base[256];
  int b = blockIdx.x, t = threadIdx.x;
  if (b < nb1) {
    // ---- bsort1 block b: BS1_TILE-edge tile, LDS hist over dst>>bsh
    // buckets, one atomicAdd per (block,bucket) reserves a staging run.
    hist[t] = 0;
    __syncthreads();
    int tile = b * BS1_TILE;
#pragma unroll
    for (int j = 0; j < BS1_TILE / 256; j++) {
      int e = tile + j * 256 + t;
      if (e < nE) atomicAdd(&hist[dst[e] >> bsh], 1);
    }
    __syncthreads();
    int cnt = hist[t];
    if (cnt > 0) base[t] = atomicAdd(&bcur[t], cnt);  // staging offset, bucket t
    hist[t] = 0;  // reuse as intra-block rank counter
    __syncthreads();
#pragma unroll
    for (int j = 0; j < BS1_TILE / 256; j++) {
      int e = tile + j * 256 + t;
      if (e < nE) {
        int d = dst[e], bk = d >> bsh;
        int r = atomicAdd(&hist[bk], 1);
        stg[(size_t)bk * cap + base[bk] + r] =
            make_uint2((unsigned)src[e], (unsigned)d | ((unsigned)et[e] << 20));
      }
    }
    return;
  }
  int b2 = b - nb1;
  if (b2 < nb_cvt) {
    int i = b2 * 256 + t;
    if (i < n4) {
      float4 v = ((const float4*)emb)[i];
      union { short s[4]; uint2 u; } o;
      o.s[0] = f2bf(v.x); o.s[1] = f2bf(v.y); o.s[2] = f2bf(v.z); o.s[3] = f2bf(v.w);
      ((uint2*)emb_h)[i] = o.u;
    }
  } else if (b2 < nb_cvt + 12) {
    int k = b2 - nb_cvt;
    for (int i = t; i < 4096; i += 256) {
      int d = i >> 6, r = i & 63;
      Bt[k * 4096 + r * 64 + d] = f2bf(Wr[k * 4096 + i]);
    }
  } else {
    int i = (b2 - nb_cvt - 12) * 256 + t;
    const float* W; short* H; short* L; int j;
    if (i < 4096) { W = W10; H = w1h0; L = w1l0; j = i; }
    else if (i < 8192) { W = W20; H = w2h0; L = w2l0; j = i - 4096; }
    else if (i < 10240) { W = W11; H = w1h1; L = w1l1; j = i - 8192; }
    else if (i < 12288) { W = W21; H = w2h1; L = w2l1; j = i - 10240; }
    else return;
    float w = W[j];
    short hi = f2bf(w);
    H[j] = hi;
    L[j] = f2bf(w - bf2f(hi));
  }
}

// proj GEMM: 64-node blocks (4 waves x 16 rows) for full CU residency
// (1563 blocks = 6.1/CU). Wave = 16 rows x 64 cols per relation, 16x16x32
// bf16 MFMA. proj PLANE-major [k][N][64]. Epilogue bounces C through a
// WAVE-PRIVATE LDS tile (stride 72 shorts) -> short8 1KB-contiguous stores.
// No barriers: intra-wave DS ops are in-order.
__global__ __launch_bounds__(256) void k_projm(const short* __restrict__ A,
                                               const short* __restrict__ Bt,
                                               short* __restrict__ proj,
                                               int n_ent) {
  __shared__ unsigned short sh[4][16 * 72];
  int wave = threadIdx.x >> 6, lane = threadIdx.x & 63;
  int quad = lane >> 4, l16 = lane & 15;
  int m0 = blockIdx.x * 64 + wave * 16;
  unsigned short* W = &sh[wave][0];
  short8 a[2];
#pragma unroll
  for (int kc = 0; kc < 2; kc++) {
    int row = m0 + l16;
    int rr = row < n_ent ? row : 0;  // clamp; clamped rows never stored
    a[kc] = *(const short8*)(A + (size_t)rr * 64 + kc * 32 + quad * 8);
  }
  for (int k = 0; k < 12; k++) {
    const short* B = Bt + k * 4096;
    short8 b[4][2];
#pragma unroll
    for (int nt = 0; nt < 4; nt++)
#pragma unroll
      for (int kc = 0; kc < 2; kc++)
        b[nt][kc] = *(const short8*)(B + (nt * 16 + l16) * 64 + kc * 32 + quad * 8);
    float4v acc[4];
#pragma unroll
    for (int nt = 0; nt < 4; nt++) acc[nt] = (float4v){0.f, 0.f, 0.f, 0.f};
#pragma unroll
    for (int kc = 0; kc < 2; kc++)
#pragma unroll
      for (int nt = 0; nt < 4; nt++)
        acc[nt] = __builtin_amdgcn_mfma_f32_16x16x32_bf16(
            a[kc], b[nt][kc], acc[nt], 0, 0, 0);
    // C layout: col = nt*16+l16, row = quad*4 + r
#pragma unroll
    for (int nt = 0; nt < 4; nt++)
#pragma unroll
      for (int r = 0; r < 4; r++)
        W[(quad * 4 + r) * 72 + nt * 16 + l16] = (unsigned short)f2bf(acc[nt][r]);
    const size_t plane = (size_t)k * n_ent;
#pragma unroll
    for (int i = 0; i < 2; i++) {
      int row = (lane >> 3) + 8 * i;
      int cs = (lane & 7) * 8;
      short8 v = *(const short8*)(W + row * 72 + cs);
      int node = m0 + row;
      if (node < n_ent)
        *(short8*)(proj + (plane + node) * 64 + cs) = v;
    }
  }
}

// Bucket-sort pass C: one block per bucket. Scans bcur itself (<=256 ints)
// for its CSR base, local LDS histogram over its <=1024 dsts, local scan ->
// per-dst offsets; writes row_ptr AND places edges. Output region
// block-exclusive -> full write combining.
__global__ __launch_bounds__(256) void k_bsort2(const uint2* __restrict__ stg,
                                                const int* __restrict__ bcur,
                                                int* __restrict__ row_ptr,
                                                uint2* __restrict__ csr2,
                                                int n, int bsh, int cap,
                                                int nbuck, int nE) {
  __shared__ int cnt[1024];
  __shared__ int sc[1024];
  __shared__ int bs[256];
  int b = blockIdx.x, t = threadIdx.x;
  // self-scan of bucket counts -> this bucket's CSR base
  int v = (t < nbuck) ? bcur[t] : 0;
  bs[t] = v;
  __syncthreads();
  for (int o = 1; o < 256; o <<= 1) {
    int a = (t >= o) ? bs[t - o] : 0;
    __syncthreads();
    bs[t] += a;
    __syncthreads();
  }
  int gbase = bs[b] - bcur[b];  // exclusive prefix at b
  int lo = b << bsh;
  if (lo > n) lo = n;
  int hi = (b + 1) << bsh;
  if (hi > n) hi = n;
  int w = hi - lo;
#pragma unroll
  for (int j = 0; j < 4; j++) cnt[t + j * 256] = 0;
  __syncthreads();
  int m = bcur[b];
  const uint2* S = stg + (size_t)b * cap;
  for (int p = t; p < m; p += 256)
    atomicAdd(&cnt[(int)(S[p].y & 0xFFFFFu) - lo], 1);
  __syncthreads();
#pragma unroll
  for (int j = 0; j < 4; j++) sc[t + j * 256] = cnt[t + j * 256];
  __syncthreads();
  for (int o = 1; o < 1024; o <<= 1) {
    int a[4];
#pragma unroll
    for (int j = 0; j < 4; j++) {
      int i = t + j * 256;
      a[j] = (i >= o) ? sc[i - o] : 0;
    }
    __syncthreads();
#pragma unroll
    for (int j = 0; j < 4; j++) sc[t + j * 256] += a[j];
    __syncthreads();
  }
#pragma unroll
  for (int j = 0; j < 4; j++) {
    int i = t + j * 256;
    if (i < w) {
      int c0 = gbase + sc[i] - cnt[i];  // exclusive offset for dst lo+i
      row_ptr[lo + i] = c0;
      cnt[i] = c0;  // reuse as global cursor
    }
  }
  if (b == nbuck - 1 && t == 0) row_ptr[n] = nE;
  __syncthreads();
  for (int p = t; p < m; p += 256) {
    uint2 vv = S[p];
    int d = (int)(vv.y & 0xFFFFFu);
    int pos = atomicAdd(&cnt[d - lo], 1);
    csr2[pos] = vv;
  }
}

// Edge scores + exp, walking edges in dst-sorted order (csr2): head gathers
// stream monotonically through each proj plane, tail gathers hit LLC behind
// the stream. ex is written IN PLACE over csr2[e].y. 8 lanes per edge
// (128B rows), 4 edge-batches per wave. proj is PLANE-major [k][N][64].
__global__ __launch_bounds__(256) void k_logits(const short* __restrict__ ps,
                                                const float* __restrict__ rel_emb,
                                                uint2* csr2, int nE, int n_ent) {
  int t = threadIdx.x;
  int lane = t & 63;
  int sub = lane >> 3;        // edge slot within wave (0..7)
  int c8 = (lane & 7) * 8;    // component group base
  int e0 = (blockIdx.x * 4 + (t >> 6)) * 32;
  if (e0 >= nE) return;
  int ku[4];
  short8 tl[4], hd[4];
#pragma unroll
  for (int u = 0; u < 4; u++) {
    int e = e0 + u * 8 + sub;
    int ee = e < nE ? e : nE - 1;
    uint2 c = csr2[ee];
    int s = (int)c.x;
    int d = (int)(c.y & 0xFFFFFu);
    int k = (int)(c.y >> 20);
    ku[u] = k;
    const size_t plane = (size_t)k * n_ent;
    tl[u] = *(const short8*)(ps + (plane + s) * 64 + c8);
    hd[u] = *(const short8*)(ps + (plane + d) * 64 + c8);
  }
  float v[4];
#pragma unroll
  for (int u = 0; u < 4; u++) {
    const float* rp = rel_emb + ku[u] * 64 + c8;
    float4 r0 = *(const float4*)rp;
    float4 r1 = *(const float4*)(rp + 4);
    float rr[8] = {r0.x, r0.y, r0.z, r0.w, r1.x, r1.y, r1.z, r1.w};
    float vv = 0.f;
#pragma unroll
    for (int q = 0; q < 8; q++) {
      float x = bf2f(hd[u][q]) + rr[q];
      // tanh(x) = 1 - 2/(exp2(2*log2e*x)+1); v_exp + v_rcp, no IEEE div
      float tt = __builtin_amdgcn_exp2f(x * (2.f * LOG2E));
      float r = __builtin_amdgcn_rcpf(tt + 1.f);
      float th = fmaf(-2.f, r, 1.f);
      vv = fmaf(bf2f(tl[u][q]), th, vv);
    }
    vv += __shfl_xor(vv, 1);
    vv += __shfl_xor(vv, 2);
    vv += __shfl_xor(vv, 4);
    v[u] = __builtin_amdgcn_exp2f(vv * LOG2E);  // e^vv; logits bounded
  }
  // One edge per lane (32 lanes): edge (u=lane&7, sub). v is uniform across
  // each sub-group of 8 lanes, so the select chain is safe.
  int uu = lane & 7;
  if (uu < 4) {
    float myv = v[0];
    if (uu == 1) myv = v[1];
    if (uu == 2) myv = v[2];
    if (uu == 3) myv = v[3];
    int e = e0 + uu * 8 + sub;
    if (e < nE) csr2[e].y = __float_as_uint(myv);
  }
}

// h_n[n,:] = (sum_j ex_j * x[src_j,:]) / den. Wave per node, lane = col.
// ONE coalesced csr load (lane=entry), shfl broadcast, den wave-reduced.
// Masked 8-wide batches: lanes >= deg hold exv=0 so OOR shfl sources add 0.
__global__ __launch_bounds__(256) void k_agg(const short* __restrict__ xh,
                                             const int* __restrict__ row_ptr,
                                             const uint2* __restrict__ csr,
                                             float* __restrict__ hn, int n_ent) {
  int wave = threadIdx.x >> 6, lane = threadIdx.x & 63;
  int n = blockIdx.x * 4 + wave;
  if (n >= n_ent) return;
  int jb = row_ptr[n], je = row_ptr[n + 1];
  int deg = je - jb;
  if (deg == 0) {
    hn[(size_t)n * 64 + lane] = 0.f;  // no edges: reference h = 0
    return;
  }
  uint2 c = (lane < deg) ? csr[jb + lane] : make_uint2(0u, 0u);
  int sidx = (int)c.x;
  float exv = (lane < deg) ? __uint_as_float(c.y) : 0.f;
  float den = exv;
#pragma unroll
  for (int o = 32; o; o >>= 1) den += __shfl_xor(den, o);
  int m = deg < 64 ? deg : 64;
  float acc = 0.f;
  for (int j = 0; j < m; j += 8) {
    int s0 = __shfl(sidx, j), s1 = __shfl(sidx, j + 1);
    int s2 = __shfl(sidx, j + 2), s3 = __shfl(sidx, j + 3);
    int s4 = __shfl(sidx, j + 4), s5 = __shfl(sidx, j + 5);
    int s6 = __shfl(sidx, j + 6), s7 = __shfl(sidx, j + 7);
    float e0 = __shfl(exv, j), e1 = __shfl(exv, j + 1);
    float e2 = __shfl(exv, j + 2), e3 = __shfl(exv, j + 3);
    float e4 = __shfl(exv, j + 4), e5 = __shfl(exv, j + 5);
    float e6 = __shfl(exv, j + 6), e7 = __shfl(exv, j + 7);
    short g0 = xh[(size_t)s0 * 64 + lane];
    short g1 = xh[(size_t)s1 * 64 + lane];
    short g2 = xh[(size_t)s2 * 64 + lane];
    short g3 = xh[(size_t)s3 * 64 + lane];
    short g4 = xh[(size_t)s4 * 64 + lane];
    short g5 = xh[(size_t)s5 * 64 + lane];
    short g6 = xh[(size_t)s6 * 64 + lane];
    short g7 = xh[(size_t)s7 * 64 + lane];
    acc = fmaf(e0, bf2f(g0), acc); acc = fmaf(e1, bf2f(g1), acc);
    acc = fmaf(e2, bf2f(g2), acc); acc = fmaf(e3, bf2f(g3), acc);
    acc = fmaf(e4, bf2f(g4), acc); acc = fmaf(e5, bf2f(g5), acc);
    acc = fmaf(e6, bf2f(g6), acc); acc = fmaf(e7, bf2f(g7), acc);
  }
  if (deg > 64) {  // rare (E/N ~ 10); broadcast loads, den stays uniform
    for (int jj = jb + 64; jj < je; jj++) {
      uint2 cc = csr[jj];
      float ee = __uint_as_float(cc.y);
      den += ee;
      acc = fmaf(ee, bf2f(xh[(size_t)cc.x * 64 + lane]), acc);
    }
  }
  hn[(size_t)n * 64 + lane] = acc / den;
}

// y = lrelu((x+h)W1^T+b1) + lrelu((x*h)W2^T+b2) via MFMA.
// Split-bf16 GEMM (3 terms) keeps f32-level accuracy. Block = 4 waves x 32
// nodes = 128 nodes. Weights (hi/lo) staged once to LDS, stride 72 shorts
// (16B-aligned rows, bank-uniform ds_read_b128). A fragments built from f32
// x/hn loads. FIRST also emits x0 passthrough, x1 f32 and x1 bf16.
template <int OD, bool FIRST>
__global__ __launch_bounds__(256) void k_upmfma(const float* __restrict__ x,
                                                const float* __restrict__ hn,
                                                const short* __restrict__ g1h,
                                                const short* __restrict__ g1l,
                                                const short* __restrict__ g2h,
                                                const short* __restrict__ g2l,
                                                const float* __restrict__ b1,
                                                const float* __restrict__ b2,
                                                float* __restrict__ out,
                                                float* __restrict__ x_next,
                                                short* __restrict__ xh_next,
                                                int n_ent) {
  constexpr int NT = OD / 16;
  __shared__ short w1h[OD * 72], w1l[OD * 72], w2h[OD * 72], w2l[OD * 72];
  int t = threadIdx.x;
  for (int i = t; i < OD * 16; i += 256) {  // uint2 = 4 shorts per slot
    int o = i >> 4, dq = (i & 15) * 4;
    *(uint2*)(w1h + o * 72 + dq) = *(const uint2*)(g1h + o * 64 + dq);
    *(uint2*)(w1l + o * 72 + dq) = *(const uint2*)(g1l + o * 64 + dq);
    *(uint2*)(w2h + o * 72 + dq) = *(const uint2*)(g2h + o * 64 + dq);
    *(uint2*)(w2l + o * 72 + dq) = *(const uint2*)(g2l + o * 64 + dq);
  }
  int wave = t >> 6, lane = t & 63;
  int quad = lane >> 4, l16 = lane & 15;
  int m0 = blockIdx.x * 128 + wave * 32;
  float4v accA[2][NT], accM[2][NT];
#pragma unroll
  for (int mt = 0; mt < 2; mt++)
#pragma unroll
    for (int nt = 0; nt < NT; nt++) {
      accA[mt][nt] = (float4v){0.f, 0.f, 0.f, 0.f};
      accM[mt][nt] = (float4v){0.f, 0.f, 0.f, 0.f};
    }
  __syncthreads();
#pragma unroll
  for (int kc = 0; kc < 2; kc++) {
    short8 ah_add[2], al_add[2], ah_mul[2], al_mul[2];
#pragma unroll
    for (int mt = 0; mt < 2; mt++) {
      int row = m0 + mt * 16 + l16;
      int rr = row < n_ent ? row : 0;  // clamp; clamped rows never stored
      const float* xp = x + (size_t)rr * 64 + kc * 32 + quad * 8;
      const float* hp = hn + (size_t)rr * 64 + kc * 32 + quad * 8;
      float4 xa = *(const float4*)xp;
      float4 xb = *(const float4*)(xp + 4);
      float4 ha = *(const float4*)hp;
      float4 hb = *(const float4*)(hp + 4);
      if (FIRST && row < n_ent) {  // x0 passthrough from the same loads
        *(float4*)(out + (size_t)row * 160 + kc * 32 + quad * 8) = xa;
        *(float4*)(out + (size_t)row * 160 + kc * 32 + quad * 8 + 4) = xb;
      }
      float xs[8] = {xa.x, xa.y, xa.z, xa.w, xb.x, xb.y, xb.z, xb.w};
      float hs[8] = {ha.x, ha.y, ha.z, ha.w, hb.x, hb.y, hb.z, hb.w};
#pragma unroll
      for (int q = 0; q < 8; q++) {
        float s = xs[q] + hs[q];
        short shi = f2bf(s);
        ah_add[mt][q] = shi;
        al_add[mt][q] = f2bf(s - bf2f(shi));
        float p = xs[q] * hs[q];
        short phi = f2bf(p);
        ah_mul[mt][q] = phi;
        al_mul[mt][q] = f2bf(p - bf2f(phi));
      }
    }
#pragma unroll
    for (int nt = 0; nt < NT; nt++) {
      int boff = (nt * 16 + l16) * 72 + kc * 32 + quad * 8;
      short8 b1h = *(const short8*)(w1h + boff);
      short8 b1l = *(const short8*)(w1l + boff);
      short8 b2h = *(const short8*)(w2h + boff);
      short8 b2l = *(const short8*)(w2l + boff);
#pragma unroll
      for (int mt = 0; mt < 2; mt++) {
        accA[mt][nt] = __builtin_amdgcn_mfma_f32_16x16x32_bf16(
            ah_add[mt], b1h, accA[mt][nt], 0, 0, 0);
        accA[mt][nt] = __builtin_amdgcn_mfma_f32_16x16x32_bf16(
            al_add[mt], b1h, accA[mt][nt], 0, 0, 0);
        accA[mt][nt] = __builtin_amdgcn_mfma_f32_16x16x32_bf16(
            ah_add[mt], b1l, accA[mt][nt], 0, 0, 0);
        accM[mt][nt] = __builtin_amdgcn_mfma_f32_16x16x32_bf16(
            ah_mul[mt], b2h, accM[mt][nt], 0, 0, 0);
        accM[mt][nt] = __builtin_amdgcn_mfma_f32_16x16x32_bf16(
            al_mul[mt], b2h, accM[mt][nt], 0, 0, 0);
        accM[mt][nt] = __builtin_amdgcn_mfma_f32_16x16x32_bf16(
            ah_mul[mt], b2l, accM[mt][nt], 0, 0, 0);
      }
    }
  }
  // C layout: col = nt*16+l16, row = mt*16 + quad*4 + r
#pragma unroll
  for (int nt = 0; nt < NT; nt++) {
    int col = nt * 16 + l16;
    float bb1 = b1[col], bb2 = b2[col];
#pragma unroll
    for (int mt = 0; mt < 2; mt++) {
#pragma unroll
      for (int r = 0; r < 4; r++) {
        int row = m0 + mt * 16 + quad * 4 + r;
        float aa = accA[mt][nt][r] + bb1;
        float mm = accM[mt][nt][r] + bb2;
        aa = aa > 0.f ? aa : 0.01f * aa;
        mm = mm > 0.f ? mm : 0.01f * mm;
        float y = aa + mm;
        if constexpr (FIRST) {
          float yn = __shfl_xor(y, 1);  // partner col^1, same row (quad equal)
          if (row < n_ent) {
            out[(size_t)row * 160 + 64 + col] = y;
            x_next[(size_t)row * 64 + col] = y;
            if ((lane & 1) == 0) {
              unsigned pk = (unsigned)(unsigned short)f2bf(y) |
                            ((unsigned)(unsigned short)f2bf(yn) << 16);
              *(unsigned*)(xh_next + (size_t)row * 64 + col) = pk;
            }
          }
        } else {
          if (row < n_ent) out[(size_t)row * 160 + 128 + col] = y;
        }
      }
    }
  }
}

extern "C" void kernel_launch(void* const* d_in, const int* in_sizes, int n_in,
                              void* d_out, int out_size, void* d_ws, size_t ws_size,
                              hipStream_t stream) {
  const float* emb = (const float*)d_in[0];
  const float* rel = (const float*)d_in[1];
  const float* Wr = (const float*)d_in[2];
  const float* W10w = (const float*)d_in[3];
  const float* W10b = (const float*)d_in[4];
  const float* W20w = (const float*)d_in[5];
  const float* W20b = (const float*)d_in[6];
  const float* W11w = (const float*)d_in[7];
  const float* W11b = (const float*)d_in[8];
  const float* W21w = (const float*)d_in[9];
  const float* W21b = (const float*)d_in[10];
  const int* src = (const int*)d_in[11];
  const int* dst = (const int*)d_in[12];
  const int* et = (const int*)d_in[13];
  int N = in_sizes[0] / 64;
  int E = in_sizes[11];
  float* out = (float*)d_out;

  int bsh = 9;
  while (((N + (1 << bsh) - 1) >> bsh) > 256) bsh++;  // nbuck <= 256
  int nbuck = (N + (1 << bsh) - 1) >> bsh;
  int cap = ((E / nbuck) * 3 / 2 + 1024 + 255) / 256 * 256;  // ~50 sigma margin

  char* p = (char*)d_ws;
  auto alloc = [&](size_t bytes) -> char* {
    char* r = p;
    p += (bytes + 255) / 256 * 256;
    return r;
  };
  short* proj = (short*)alloc((size_t)N * 768 * 2);
  uint2* csr2 = (uint2*)alloc((size_t)E * 8);  // final CSR {src, dst|et} -> {src, ex}
  uint2* stg = (uint2*)alloc((size_t)nbuck * cap * 8);  // per-bucket staging
  int* row_ptr = (int*)alloc((size_t)(N + 1) * 4);
  int* bcur = (int*)alloc(1024);               // bucket staging cursors
  float* hn = (float*)alloc((size_t)N * 64 * 4);
  float* x1 = (float*)alloc((size_t)N * 64 * 4);
  short* emb_h = (short*)alloc(((size_t)N + 128) * 64 * 2);  // bf16 emb, padded
  short* x1h = (short*)alloc(((size_t)N + 128) * 64 * 2);    // bf16 x1
  short* Bt = (short*)alloc((size_t)12 * 4096 * 2);          // bf16 W_r^T
  short* w1h0 = (short*)alloc(4096 * 2);                     // layer-weight hi/lo
  short* w1l0 = (short*)alloc(4096 * 2);
  short* w2h0 = (short*)alloc(4096 * 2);
  short* w2l0 = (short*)alloc(4096 * 2);
  short* w1h1 = (short*)alloc(2048 * 2);
  short* w1l1 = (short*)alloc(2048 * 2);
  short* w2h1 = (short*)alloc(2048 * 2);
  short* w2l1 = (short*)alloc(2048 * 2);

  int n4 = N * 16;
  int nb_cvt = (n4 + 255) / 256;
  int nb1 = (E + BS1_TILE - 1) / BS1_TILE;  // bsort1 blocks (merged into prep)

  hipMemsetAsync(bcur, 0, 1024, stream);
  k_prep<<<nb1 + nb_cvt + 60, 256, 0, stream>>>(
      emb, emb_h, Wr, Bt, W10w, W20w, W11w, W21w,
      w1h0, w1l0, w2h0, w2l0, w1h1, w1l1, w2h1, w2l1,
      src, dst, et, bcur, stg, E, bsh, cap, nb1, nb_cvt, n4);
  k_projm<<<(N + 63) / 64, 256, 0, stream>>>(emb_h, Bt, proj, N);
  k_bsort2<<<nbuck, 256, 0, stream>>>(stg, bcur, row_ptr, csr2, N, bsh, cap, nbuck, E);
  k_logits<<<(E + 127) / 128, 256, 0, stream>>>(proj, rel, csr2, E, N);
  k_agg<<<(N + 3) / 4, 256, 0, stream>>>(emb_h, row_ptr, csr2, hn, N);
  k_upmfma<64, true><<<(N + 127) / 128, 256, 0, stream>>>(
      emb, hn, w1h0, w1l0, w2h0, w2l0, W10b, W20b, out, x1, x1h, N);
  k_agg<<<(N + 3) / 4, 256, 0, stream>>>(x1h, row_ptr, csr2, hn, N);
  k_upmfma<32, false><<<(N + 127) / 128, 256, 0, stream>>>(
      x1, hn, w1h1, w1l1, w2h1, w2l1, W11b, W21b, out, nullptr, nullptr, N);
}

// Round 11
// 380.325 us; speedup vs baseline: 1.0951x; 1.0951x over previous
//
#include <hip/hip_runtime.h>
#include <hip/hip_bf16.h>
#include <math.h>

// ---------------------------------------------------------------------------
// KGAT on MI355X.
//   N = 100000 entities, R = 12 relations, D = 64, E = 1e6 edges.
//   proj[k,n,r] = sum_d emb[n,d] * W_r[k,d,r]   -> bf16 MFMA GEMM (PLANE-major)
//   logits[e]   = sum_r proj[et,src,r] * tanh(proj[et,dst,r] + rel[et,r])
//   att         = edge_softmax(logits, by dst)  (unnormalized exp; logits bounded)
//   layer(x):   h = segsum(x[src]*att -> dst); y = lrelu((x+h)W1^T+b1)+lrelu((x*h)W2^T+b2)
//   out = [x0 | x1 | x2]  row stride 160 (f32)
// R18: R17's 64-node projm tile REGRESSED (60->88us) despite 2x occupancy:
//     per-wave B-operand traffic is constant (full 64x64 Bt tile per k), so
//     halving rows halved MFMA per wave -> per-MFMA issue overhead doubled.
//     The kernel is issue-bound, not occupancy-bound; bigger M-tile = better
//     B reuse. REVERTED projm to the R16 128-node body (60us measured).
//     KEPT R17's wins: bsort1 at 2048-edge tiles (+~18us in prep) and
//     bscan-deletion (bsort2 self-scans bcur).
// ---------------------------------------------------------------------------

typedef __attribute__((ext_vector_type(8))) short short8;   // 8 bf16 (4 VGPR)
typedef __attribute__((ext_vector_type(4))) float float4v;  // MFMA acc

__device__ __forceinline__ short f2bf(float f) {
  __hip_bfloat16 h = __float2bfloat16(f);
  return *(short*)&h;
}
__device__ __forceinline__ float bf2f(short s) {
  return __uint_as_float(((unsigned)(unsigned short)s) << 16);
}

#define LOG2E 1.4426950408889634f
#define BS1_TILE 2048

// Merged prep: [0,nb1) bucket-sort pass B (latency-bound, starts at t=0) |
// then emb f32->bf16 | 12 blocks W_r transpose+cvt | 48 blocks layer-weight
// hi/lo bf16 split.
__global__ void k_prep(const float* __restrict__ emb, short* __restrict__ emb_h,
                       const float* __restrict__ Wr, short* __restrict__ Bt,
                       const float* __restrict__ W10, const float* __restrict__ W20,
                       const float* __restrict__ W11, const float* __restrict__ W21,
                       short* __restrict__ w1h0, short* __restrict__ w1l0,
                       short* __restrict__ w2h0, short* __restrict__ w2l0,
                       short* __restrict__ w1h1, short* __restrict__ w1l1,
                       short* __restrict__ w2h1, short* __restrict__ w2l1,
                       const int* __restrict__ src, const int* __restrict__ dst,
                       const int* __restrict__ et, int* __restrict__ bcur,
                       uint2* __restrict__ stg, int nE, int bsh, int cap,
                       int nb1, int nb_cvt, int n4) {
  __shared__ int hist[256];
  __shared__ int base[256];
  int b = blockIdx.x, t = threadIdx.x;
  if (b < nb1) {
    // ---- bsort1 block b: BS1_TILE-edge tile, LDS hist over dst>>bsh
    // buckets, one atomicAdd per (block,bucket) reserves a staging run.
    hist[t] = 0;
    __syncthreads();
    int tile = b * BS1_TILE;
#pragma unroll
    for (int j = 0; j < BS1_TILE / 256; j++) {
      int e = tile + j * 256 + t;
      if (e < nE) atomicAdd(&hist[dst[e] >> bsh], 1);
    }
    __syncthreads();
    int cnt = hist[t];
    if (cnt > 0) base[t] = atomicAdd(&bcur[t], cnt);  // staging offset, bucket t
    hist[t] = 0;  // reuse as intra-block rank counter
    __syncthreads();
#pragma unroll
    for (int j = 0; j < BS1_TILE / 256; j++) {
      int e = tile + j * 256 + t;
      if (e < nE) {
        int d = dst[e], bk = d >> bsh;
        int r = atomicAdd(&hist[bk], 1);
        stg[(size_t)bk * cap + base[bk] + r] =
            make_uint2((unsigned)src[e], (unsigned)d | ((unsigned)et[e] << 20));
      }
    }
    return;
  }
  int b2 = b - nb1;
  if (b2 < nb_cvt) {
    int i = b2 * 256 + t;
    if (i < n4) {
      float4 v = ((const float4*)emb)[i];
      union { short s[4]; uint2 u; } o;
      o.s[0] = f2bf(v.x); o.s[1] = f2bf(v.y); o.s[2] = f2bf(v.z); o.s[3] = f2bf(v.w);
      ((uint2*)emb_h)[i] = o.u;
    }
  } else if (b2 < nb_cvt + 12) {
    int k = b2 - nb_cvt;
    for (int i = t; i < 4096; i += 256) {
      int d = i >> 6, r = i & 63;
      Bt[k * 4096 + r * 64 + d] = f2bf(Wr[k * 4096 + i]);
    }
  } else {
    int i = (b2 - nb_cvt - 12) * 256 + t;
    const float* W; short* H; short* L; int j;
    if (i < 4096) { W = W10; H = w1h0; L = w1l0; j = i; }
    else if (i < 8192) { W = W20; H = w2h0; L = w2l0; j = i - 4096; }
    else if (i < 10240) { W = W11; H = w1h1; L = w1l1; j = i - 8192; }
    else if (i < 12288) { W = W21; H = w2h1; L = w2l1; j = i - 10240; }
    else return;
    float w = W[j];
    short hi = f2bf(w);
    H[j] = hi;
    L[j] = f2bf(w - bf2f(hi));
  }
}

// proj GEMM (R16-verified, 60us): 128-node blocks, wave = 32 rows x 64 cols
// per relation, 16x16x32 bf16 MFMA (16 MFMA : 8 B-loads per wave-k). proj is
// PLANE-major [k][N][64]: per-block per-k store = 16KB contiguous. Epilogue
// bounces C through a WAVE-PRIVATE LDS tile (stride 72 shorts) -> short8
// 1KB-contiguous stores. No barriers: intra-wave DS ops are in-order.
__global__ __launch_bounds__(256) void k_projm(const short* __restrict__ A,
                                               const short* __restrict__ Bt,
                                               short* __restrict__ proj,
                                               int n_ent) {
  __shared__ unsigned short sh[4][32 * 72];
  int wave = threadIdx.x >> 6, lane = threadIdx.x & 63;
  int quad = lane >> 4, l16 = lane & 15;
  int m0 = blockIdx.x * 128 + wave * 32;
  unsigned short* W = &sh[wave][0];
  short8 a[2][2];
#pragma unroll
  for (int mt = 0; mt < 2; mt++)
#pragma unroll
    for (int kc = 0; kc < 2; kc++) {
      int row = m0 + mt * 16 + l16;
      int rr = row < n_ent ? row : 0;  // clamp; clamped rows never stored
      a[mt][kc] = *(const short8*)(A + (size_t)rr * 64 + kc * 32 + quad * 8);
    }
  for (int k = 0; k < 12; k++) {
    const short* B = Bt + k * 4096;
    short8 b[4][2];
#pragma unroll
    for (int nt = 0; nt < 4; nt++)
#pragma unroll
      for (int kc = 0; kc < 2; kc++)
        b[nt][kc] = *(const short8*)(B + (nt * 16 + l16) * 64 + kc * 32 + quad * 8);
    float4v acc[2][4];
#pragma unroll
    for (int mt = 0; mt < 2; mt++)
#pragma unroll
      for (int nt = 0; nt < 4; nt++)
        acc[mt][nt] = (float4v){0.f, 0.f, 0.f, 0.f};
#pragma unroll
    for (int kc = 0; kc < 2; kc++)
#pragma unroll
      for (int mt = 0; mt < 2; mt++)
#pragma unroll
        for (int nt = 0; nt < 4; nt++)
          acc[mt][nt] = __builtin_amdgcn_mfma_f32_16x16x32_bf16(
              a[mt][kc], b[nt][kc], acc[mt][nt], 0, 0, 0);
    // C layout: col = nt*16+l16, row = mt*16 + quad*4 + r
#pragma unroll
    for (int mt = 0; mt < 2; mt++)
#pragma unroll
      for (int nt = 0; nt < 4; nt++)
#pragma unroll
        for (int r = 0; r < 4; r++) {
          int row = mt * 16 + quad * 4 + r;
          int col = nt * 16 + l16;
          W[row * 72 + col] = (unsigned short)f2bf(acc[mt][nt][r]);
        }
    const size_t plane = (size_t)k * n_ent;
#pragma unroll
    for (int i = 0; i < 4; i++) {
      int row = (lane >> 3) + 8 * i;
      int cs = (lane & 7) * 8;
      short8 v = *(const short8*)(W + row * 72 + cs);
      int node = m0 + row;
      if (node < n_ent)
        *(short8*)(proj + (plane + node) * 64 + cs) = v;
    }
  }
}

// Bucket-sort pass C: one block per bucket. Scans bcur itself (<=256 ints)
// for its CSR base, local LDS histogram over its <=1024 dsts, local scan ->
// per-dst offsets; writes row_ptr AND places edges. Output region
// block-exclusive -> full write combining.
__global__ __launch_bounds__(256) void k_bsort2(const uint2* __restrict__ stg,
                                                const int* __restrict__ bcur,
                                                int* __restrict__ row_ptr,
                                                uint2* __restrict__ csr2,
                                                int n, int bsh, int cap,
                                                int nbuck, int nE) {
  __shared__ int cnt[1024];
  __shared__ int sc[1024];
  __shared__ int bs[256];
  int b = blockIdx.x, t = threadIdx.x;
  // self-scan of bucket counts -> this bucket's CSR base
  int v = (t < nbuck) ? bcur[t] : 0;
  bs[t] = v;
  __syncthreads();
  for (int o = 1; o < 256; o <<= 1) {
    int a = (t >= o) ? bs[t - o] : 0;
    __syncthreads();
    bs[t] += a;
    __syncthreads();
  }
  int gbase = bs[b] - bcur[b];  // exclusive prefix at b
  int lo = b << bsh;
  if (lo > n) lo = n;
  int hi = (b + 1) << bsh;
  if (hi > n) hi = n;
  int w = hi - lo;
#pragma unroll
  for (int j = 0; j < 4; j++) cnt[t + j * 256] = 0;
  __syncthreads();
  int m = bcur[b];
  const uint2* S = stg + (size_t)b * cap;
  for (int p = t; p < m; p += 256)
    atomicAdd(&cnt[(int)(S[p].y & 0xFFFFFu) - lo], 1);
  __syncthreads();
#pragma unroll
  for (int j = 0; j < 4; j++) sc[t + j * 256] = cnt[t + j * 256];
  __syncthreads();
  for (int o = 1; o < 1024; o <<= 1) {
    int a[4];
#pragma unroll
    for (int j = 0; j < 4; j++) {
      int i = t + j * 256;
      a[j] = (i >= o) ? sc[i - o] : 0;
    }
    __syncthreads();
#pragma unroll
    for (int j = 0; j < 4; j++) sc[t + j * 256] += a[j];
    __syncthreads();
  }
#pragma unroll
  for (int j = 0; j < 4; j++) {
    int i = t + j * 256;
    if (i < w) {
      int c0 = gbase + sc[i] - cnt[i];  // exclusive offset for dst lo+i
      row_ptr[lo + i] = c0;
      cnt[i] = c0;  // reuse as global cursor
    }
  }
  if (b == nbuck - 1 && t == 0) row_ptr[n] = nE;
  __syncthreads();
  for (int p = t; p < m; p += 256) {
    uint2 vv = S[p];
    int d = (int)(vv.y & 0xFFFFFu);
    int pos = atomicAdd(&cnt[d - lo], 1);
    csr2[pos] = vv;
  }
}

// Edge scores + exp, walking edges in dst-sorted order (csr2): head gathers
// stream monotonically through each proj plane, tail gathers hit LLC behind
// the stream. ex is written IN PLACE over csr2[e].y. 8 lanes per edge
// (128B rows), 4 edge-batches per wave. proj is PLANE-major [k][N][64].
__global__ __launch_bounds__(256) void k_logits(const short* __restrict__ ps,
                                                const float* __restrict__ rel_emb,
                                                uint2* csr2, int nE, int n_ent) {
  int t = threadIdx.x;
  int lane = t & 63;
  int sub = lane >> 3;        // edge slot within wave (0..7)
  int c8 = (lane & 7) * 8;    // component group base
  int e0 = (blockIdx.x * 4 + (t >> 6)) * 32;
  if (e0 >= nE) return;
  int ku[4];
  short8 tl[4], hd[4];
#pragma unroll
  for (int u = 0; u < 4; u++) {
    int e = e0 + u * 8 + sub;
    int ee = e < nE ? e : nE - 1;
    uint2 c = csr2[ee];
    int s = (int)c.x;
    int d = (int)(c.y & 0xFFFFFu);
    int k = (int)(c.y >> 20);
    ku[u] = k;
    const size_t plane = (size_t)k * n_ent;
    tl[u] = *(const short8*)(ps + (plane + s) * 64 + c8);
    hd[u] = *(const short8*)(ps + (plane + d) * 64 + c8);
  }
  float v[4];
#pragma unroll
  for (int u = 0; u < 4; u++) {
    const float* rp = rel_emb + ku[u] * 64 + c8;
    float4 r0 = *(const float4*)rp;
    float4 r1 = *(const float4*)(rp + 4);
    float rr[8] = {r0.x, r0.y, r0.z, r0.w, r1.x, r1.y, r1.z, r1.w};
    float vv = 0.f;
#pragma unroll
    for (int q = 0; q < 8; q++) {
      float x = bf2f(hd[u][q]) + rr[q];
      // tanh(x) = 1 - 2/(exp2(2*log2e*x)+1); v_exp + v_rcp, no IEEE div
      float tt = __builtin_amdgcn_exp2f(x * (2.f * LOG2E));
      float r = __builtin_amdgcn_rcpf(tt + 1.f);
      float th = fmaf(-2.f, r, 1.f);
      vv = fmaf(bf2f(tl[u][q]), th, vv);
    }
    vv += __shfl_xor(vv, 1);
    vv += __shfl_xor(vv, 2);
    vv += __shfl_xor(vv, 4);
    v[u] = __builtin_amdgcn_exp2f(vv * LOG2E);  // e^vv; logits bounded
  }
  // One edge per lane (32 lanes): edge (u=lane&7, sub). v is uniform across
  // each sub-group of 8 lanes, so the select chain is safe.
  int uu = lane & 7;
  if (uu < 4) {
    float myv = v[0];
    if (uu == 1) myv = v[1];
    if (uu == 2) myv = v[2];
    if (uu == 3) myv = v[3];
    int e = e0 + uu * 8 + sub;
    if (e < nE) csr2[e].y = __float_as_uint(myv);
  }
}

// h_n[n,:] = (sum_j ex_j * x[src_j,:]) / den. Wave per node, lane = col.
// ONE coalesced csr load (lane=entry), shfl broadcast, den wave-reduced.
// Masked 8-wide batches: lanes >= deg hold exv=0 so OOR shfl sources add 0.
__global__ __launch_bounds__(256) void k_agg(const short* __restrict__ xh,
                                             const int* __restrict__ row_ptr,
                                             const uint2* __restrict__ csr,
                                             float* __restrict__ hn, int n_ent) {
  int wave = threadIdx.x >> 6, lane = threadIdx.x & 63;
  int n = blockIdx.x * 4 + wave;
  if (n >= n_ent) return;
  int jb = row_ptr[n], je = row_ptr[n + 1];
  int deg = je - jb;
  if (deg == 0) {
    hn[(size_t)n * 64 + lane] = 0.f;  // no edges: reference h = 0
    return;
  }
  uint2 c = (lane < deg) ? csr[jb + lane] : make_uint2(0u, 0u);
  int sidx = (int)c.x;
  float exv = (lane < deg) ? __uint_as_float(c.y) : 0.f;
  float den = exv;
#pragma unroll
  for (int o = 32; o; o >>= 1) den += __shfl_xor(den, o);
  int m = deg < 64 ? deg : 64;
  float acc = 0.f;
  for (int j = 0; j < m; j += 8) {
    int s0 = __shfl(sidx, j), s1 = __shfl(sidx, j + 1);
    int s2 = __shfl(sidx, j + 2), s3 = __shfl(sidx, j + 3);
    int s4 = __shfl(sidx, j + 4), s5 = __shfl(sidx, j + 5);
    int s6 = __shfl(sidx, j + 6), s7 = __shfl(sidx, j + 7);
    float e0 = __shfl(exv, j), e1 = __shfl(exv, j + 1);
    float e2 = __shfl(exv, j + 2), e3 = __shfl(exv, j + 3);
    float e4 = __shfl(exv, j + 4), e5 = __shfl(exv, j + 5);
    float e6 = __shfl(exv, j + 6), e7 = __shfl(exv, j + 7);
    short g0 = xh[(size_t)s0 * 64 + lane];
    short g1 = xh[(size_t)s1 * 64 + lane];
    short g2 = xh[(size_t)s2 * 64 + lane];
    short g3 = xh[(size_t)s3 * 64 + lane];
    short g4 = xh[(size_t)s4 * 64 + lane];
    short g5 = xh[(size_t)s5 * 64 + lane];
    short g6 = xh[(size_t)s6 * 64 + lane];
    short g7 = xh[(size_t)s7 * 64 + lane];
    acc = fmaf(e0, bf2f(g0), acc); acc = fmaf(e1, bf2f(g1), acc);
    acc = fmaf(e2, bf2f(g2), acc); acc = fmaf(e3, bf2f(g3), acc);
    acc = fmaf(e4, bf2f(g4), acc); acc = fmaf(e5, bf2f(g5), acc);
    acc = fmaf(e6, bf2f(g6), acc); acc = fmaf(e7, bf2f(g7), acc);
  }
  if (deg > 64) {  // rare (E/N ~ 10); broadcast loads, den stays uniform
    for (int jj = jb + 64; jj < je; jj++) {
      uint2 cc = csr[jj];
      float ee = __uint_as_float(cc.y);
      den += ee;
      acc = fmaf(ee, bf2f(xh[(size_t)cc.x * 64 + lane]), acc);
    }
  }
  hn[(size_t)n * 64 + lane] = acc / den;
}

// y = lrelu((x+h)W1^T+b1) + lrelu((x*h)W2^T+b2) via MFMA.
// Split-bf16 GEMM (3 terms) keeps f32-level accuracy. Block = 4 waves x 32
// nodes = 128 nodes. Weights (hi/lo) staged once to LDS, stride 72 shorts
// (16B-aligned rows, bank-uniform ds_read_b128). A fragments built from f32
// x/hn loads. FIRST also emits x0 passthrough, x1 f32 and x1 bf16.
template <int OD, bool FIRST>
__global__ __launch_bounds__(256) void k_upmfma(const float* __restrict__ x,
                                                const float* __restrict__ hn,
                                                const short* __restrict__ g1h,
                                                const short* __restrict__ g1l,
                                                const short* __restrict__ g2h,
                                                const short* __restrict__ g2l,
                                                const float* __restrict__ b1,
                                                const float* __restrict__ b2,
                                                float* __restrict__ out,
                                                float* __restrict__ x_next,
                                                short* __restrict__ xh_next,
                                                int n_ent) {
  constexpr int NT = OD / 16;
  __shared__ short w1h[OD * 72], w1l[OD * 72], w2h[OD * 72], w2l[OD * 72];
  int t = threadIdx.x;
  for (int i = t; i < OD * 16; i += 256) {  // uint2 = 4 shorts per slot
    int o = i >> 4, dq = (i & 15) * 4;
    *(uint2*)(w1h + o * 72 + dq) = *(const uint2*)(g1h + o * 64 + dq);
    *(uint2*)(w1l + o * 72 + dq) = *(const uint2*)(g1l + o * 64 + dq);
    *(uint2*)(w2h + o * 72 + dq) = *(const uint2*)(g2h + o * 64 + dq);
    *(uint2*)(w2l + o * 72 + dq) = *(const uint2*)(g2l + o * 64 + dq);
  }
  int wave = t >> 6, lane = t & 63;
  int quad = lane >> 4, l16 = lane & 15;
  int m0 = blockIdx.x * 128 + wave * 32;
  float4v accA[2][NT], accM[2][NT];
#pragma unroll
  for (int mt = 0; mt < 2; mt++)
#pragma unroll
    for (int nt = 0; nt < NT; nt++) {
      accA[mt][nt] = (float4v){0.f, 0.f, 0.f, 0.f};
      accM[mt][nt] = (float4v){0.f, 0.f, 0.f, 0.f};
    }
  __syncthreads();
#pragma unroll
  for (int kc = 0; kc < 2; kc++) {
    short8 ah_add[2], al_add[2], ah_mul[2], al_mul[2];
#pragma unroll
    for (int mt = 0; mt < 2; mt++) {
      int row = m0 + mt * 16 + l16;
      int rr = row < n_ent ? row : 0;  // clamp; clamped rows never stored
      const float* xp = x + (size_t)rr * 64 + kc * 32 + quad * 8;
      const float* hp = hn + (size_t)rr * 64 + kc * 32 + quad * 8;
      float4 xa = *(const float4*)xp;
      float4 xb = *(const float4*)(xp + 4);
      float4 ha = *(const float4*)hp;
      float4 hb = *(const float4*)(hp + 4);
      if (FIRST && row < n_ent) {  // x0 passthrough from the same loads
        *(float4*)(out + (size_t)row * 160 + kc * 32 + quad * 8) = xa;
        *(float4*)(out + (size_t)row * 160 + kc * 32 + quad * 8 + 4) = xb;
      }
      float xs[8] = {xa.x, xa.y, xa.z, xa.w, xb.x, xb.y, xb.z, xb.w};
      float hs[8] = {ha.x, ha.y, ha.z, ha.w, hb.x, hb.y, hb.z, hb.w};
#pragma unroll
      for (int q = 0; q < 8; q++) {
        float s = xs[q] + hs[q];
        short shi = f2bf(s);
        ah_add[mt][q] = shi;
        al_add[mt][q] = f2bf(s - bf2f(shi));
        float p = xs[q] * hs[q];
        short phi = f2bf(p);
        ah_mul[mt][q] = phi;
        al_mul[mt][q] = f2bf(p - bf2f(phi));
      }
    }
#pragma unroll
    for (int nt = 0; nt < NT; nt++) {
      int boff = (nt * 16 + l16) * 72 + kc * 32 + quad * 8;
      short8 b1h = *(const short8*)(w1h + boff);
      short8 b1l = *(const short8*)(w1l + boff);
      short8 b2h = *(const short8*)(w2h + boff);
      short8 b2l = *(const short8*)(w2l + boff);
#pragma unroll
      for (int mt = 0; mt < 2; mt++) {
        accA[mt][nt] = __builtin_amdgcn_mfma_f32_16x16x32_bf16(
            ah_add[mt], b1h, accA[mt][nt], 0, 0, 0);
        accA[mt][nt] = __builtin_amdgcn_mfma_f32_16x16x32_bf16(
            al_add[mt], b1h, accA[mt][nt], 0, 0, 0);
        accA[mt][nt] = __builtin_amdgcn_mfma_f32_16x16x32_bf16(
            ah_add[mt], b1l, accA[mt][nt], 0, 0, 0);
        accM[mt][nt] = __builtin_amdgcn_mfma_f32_16x16x32_bf16(
            ah_mul[mt], b2h, accM[mt][nt], 0, 0, 0);
        accM[mt][nt] = __builtin_amdgcn_mfma_f32_16x16x32_bf16(
            al_mul[mt], b2h, accM[mt][nt], 0, 0, 0);
        accM[mt][nt] = __builtin_amdgcn_mfma_f32_16x16x32_bf16(
            ah_mul[mt], b2l, accM[mt][nt], 0, 0, 0);
      }
    }
  }
  // C layout: col = nt*16+l16, row = mt*16 + quad*4 + r
#pragma unroll
  for (int nt = 0; nt < NT; nt++) {
    int col = nt * 16 + l16;
    float bb1 = b1[col], bb2 = b2[col];
#pragma unroll
    for (int mt = 0; mt < 2; mt++) {
#pragma unroll
      for (int r = 0; r < 4; r++) {
        int row = m0 + mt * 16 + quad * 4 + r;
        float aa = accA[mt][nt][r] + bb1;
        float mm = accM[mt][nt][r] + bb2;
        aa = aa > 0.f ? aa : 0.01f * aa;
        mm = mm > 0.f ? mm : 0.01f * mm;
        float y = aa + mm;
        if constexpr (FIRST) {
          float yn = __shfl_xor(y, 1);  // partner col^1, same row (quad equal)
          if (row < n_ent) {
            out[(size_t)row * 160 + 64 + col] = y;
            x_next[(size_t)row * 64 + col] = y;
            if ((lane & 1) == 0) {
              unsigned pk = (unsigned)(unsigned short)f2bf(y) |
                            ((unsigned)(unsigned short)f2bf(yn) << 16);
              *(unsigned*)(xh_next + (size_t)row * 64 + col) = pk;
            }
          }
        } else {
          if (row < n_ent) out[(size_t)row * 160 + 128 + col] = y;
        }
      }
    }
  }
}

extern "C" void kernel_launch(void* const* d_in, const int* in_sizes, int n_in,
                              void* d_out, int out_size, void* d_ws, size_t ws_size,
                              hipStream_t stream) {
  const float* emb = (const float*)d_in[0];
  const float* rel = (const float*)d_in[1];
  const float* Wr = (const float*)d_in[2];
  const float* W10w = (const float*)d_in[3];
  const float* W10b = (const float*)d_in[4];
  const float* W20w = (const float*)d_in[5];
  const float* W20b = (const float*)d_in[6];
  const float* W11w = (const float*)d_in[7];
  const float* W11b = (const float*)d_in[8];
  const float* W21w = (const float*)d_in[9];
  const float* W21b = (const float*)d_in[10];
  const int* src = (const int*)d_in[11];
  const int* dst = (const int*)d_in[12];
  const int* et = (const int*)d_in[13];
  int N = in_sizes[0] / 64;
  int E = in_sizes[11];
  float* out = (float*)d_out;

  int bsh = 9;
  while (((N + (1 << bsh) - 1) >> bsh) > 256) bsh++;  // nbuck <= 256
  int nbuck = (N + (1 << bsh) - 1) >> bsh;
  int cap = ((E / nbuck) * 3 / 2 + 1024 + 255) / 256 * 256;  // ~50 sigma margin

  char* p = (char*)d_ws;
  auto alloc = [&](size_t bytes) -> char* {
    char* r = p;
    p += (bytes + 255) / 256 * 256;
    return r;
  };
  short* proj = (short*)alloc((size_t)N * 768 * 2);
  uint2* csr2 = (uint2*)alloc((size_t)E * 8);  // final CSR {src, dst|et} -> {src, ex}
  uint2* stg = (uint2*)alloc((size_t)nbuck * cap * 8);  // per-bucket staging
  int* row_ptr = (int*)alloc((size_t)(N + 1) * 4);
  int* bcur = (int*)alloc(1024);               // bucket staging cursors
  float* hn = (float*)alloc((size_t)N * 64 * 4);
  float* x1 = (float*)alloc((size_t)N * 64 * 4);
  short* emb_h = (short*)alloc(((size_t)N + 128) * 64 * 2);  // bf16 emb, padded
  short* x1h = (short*)alloc(((size_t)N + 128) * 64 * 2);    // bf16 x1
  short* Bt = (short*)alloc((size_t)12 * 4096 * 2);          // bf16 W_r^T
  short* w1h0 = (short*)alloc(4096 * 2);                     // layer-weight hi/lo
  short* w1l0 = (short*)alloc(4096 * 2);
  short* w2h0 = (short*)alloc(4096 * 2);
  short* w2l0 = (short*)alloc(4096 * 2);
  short* w1h1 = (short*)alloc(2048 * 2);
  short* w1l1 = (short*)alloc(2048 * 2);
  short* w2h1 = (short*)alloc(2048 * 2);
  short* w2l1 = (short*)alloc(2048 * 2);

  int n4 = N * 16;
  int nb_cvt = (n4 + 255) / 256;
  int nb1 = (E + BS1_TILE - 1) / BS1_TILE;  // bsort1 blocks (merged into prep)

  hipMemsetAsync(bcur, 0, 1024, stream);
  k_prep<<<nb1 + nb_cvt + 60, 256, 0, stream>>>(
      emb, emb_h, Wr, Bt, W10w, W20w, W11w, W21w,
      w1h0, w1l0, w2h0, w2l0, w1h1, w1l1, w2h1, w2l1,
      src, dst, et, bcur, stg, E, bsh, cap, nb1, nb_cvt, n4);
  k_projm<<<(N + 127) / 128, 256, 0, stream>>>(emb_h, Bt, proj, N);
  k_bsort2<<<nbuck, 256, 0, stream>>>(stg, bcur, row_ptr, csr2, N, bsh, cap, nbuck, E);
  k_logits<<<(E + 127) / 128, 256, 0, stream>>>(proj, rel, csr2, E, N);
  k_agg<<<(N + 3) / 4, 256, 0, stream>>>(emb_h, row_ptr, csr2, hn, N);
  k_upmfma<64, true><<<(N + 127) / 128, 256, 0, stream>>>(
      emb, hn, w1h0, w1l0, w2h0, w2l0, W10b, W20b, out, x1, x1h, N);
  k_agg<<<(N + 3) / 4, 256, 0, stream>>>(x1h, row_ptr, csr2, hn, N);
  k_upmfma<32, false><<<(N + 127) / 128, 256, 0, stream>>>(
      x1, hn, w1h1, w1l1, w2h1, w2l1, W11b, W21b, out, nullptr, nullptr, N);
}

// Round 12
// 378.330 us; speedup vs baseline: 1.1009x; 1.0053x over previous
//
#include <hip/hip_runtime.h>
#include <hip/hip_bf16.h>
#include <math.h>

// ---------------------------------------------------------------------------
// KGAT on MI355X.
//   N = 100000 entities, R = 12 relations, D = 64, E = 1e6 edges.
//   proj[k,n,r] = sum_d emb[n,d] * W_r[k,d,r]   -> bf16 MFMA GEMM (PLANE-major)
//   logits[e]   = sum_r proj[et,src,r] * tanh(proj[et,dst,r] + rel[et,r])
//   att         = edge_softmax(logits, by dst)  (unnormalized exp; logits bounded)
//   layer(x):   h = segsum(x[src]*att -> dst); y = lrelu((x+h)W1^T+b1)+lrelu((x*h)W2^T+b2)
//   out = [x0 | x1 | x2]  row stride 160 (f32)
// R19: k_upmfma was store-request-bound (64us, 2.1 TB/s, MfmaUtil 2.7%,
//     WRITE 107MB vs 90MB payload): ~96 scalar f32 stores/thread, wave-stores
//     fragmenting to 4x64B (y) and 16x16B (x0 passthrough, l16 = row).
//     (a) LDS-bounce epilogue REUSING the weight LDS (dead after a barrier):
//         per-wave f32 y-tile stride 66/34 (=2 mod 8 -> 2-way banks, free);
//         lane reads a row float4 -> full-line stores (y 256B, x1 256B,
//         x1h 128B per row); bf16 pack needs no shfl.
//     (b) x0 passthrough moved to k_prep (it already loads every emb float4;
//         spare BW there) -- worst fragmented store deleted from upmfma.
// ---------------------------------------------------------------------------

typedef __attribute__((ext_vector_type(8))) short short8;   // 8 bf16 (4 VGPR)
typedef __attribute__((ext_vector_type(4))) float float4v;  // MFMA acc

__device__ __forceinline__ short f2bf(float f) {
  __hip_bfloat16 h = __float2bfloat16(f);
  return *(short*)&h;
}
__device__ __forceinline__ float bf2f(short s) {
  return __uint_as_float(((unsigned)(unsigned short)s) << 16);
}

#define LOG2E 1.4426950408889634f
#define BS1_TILE 2048

// Merged prep: [0,nb1) bucket-sort pass B (latency-bound, starts at t=0) |
// then emb f32->bf16 + x0 passthrough to out | 12 blocks W_r transpose+cvt |
// 48 blocks layer-weight hi/lo bf16 split.
__global__ void k_prep(const float* __restrict__ emb, short* __restrict__ emb_h,
                       float* __restrict__ out,
                       const float* __restrict__ Wr, short* __restrict__ Bt,
                       const float* __restrict__ W10, const float* __restrict__ W20,
                       const float* __restrict__ W11, const float* __restrict__ W21,
                       short* __restrict__ w1h0, short* __restrict__ w1l0,
                       short* __restrict__ w2h0, short* __restrict__ w2l0,
                       short* __restrict__ w1h1, short* __restrict__ w1l1,
                       short* __restrict__ w2h1, short* __restrict__ w2l1,
                       const int* __restrict__ src, const int* __restrict__ dst,
                       const int* __restrict__ et, int* __restrict__ bcur,
                       uint2* __restrict__ stg, int nE, int bsh, int cap,
                       int nb1, int nb_cvt, int n4) {
  __shared__ int hist[256];
  __shared__ int base[256];
  int b = blockIdx.x, t = threadIdx.x;
  if (b < nb1) {
    // ---- bsort1 block b: BS1_TILE-edge tile, LDS hist over dst>>bsh
    // buckets, one atomicAdd per (block,bucket) reserves a staging run.
    hist[t] = 0;
    __syncthreads();
    int tile = b * BS1_TILE;
#pragma unroll
    for (int j = 0; j < BS1_TILE / 256; j++) {
      int e = tile + j * 256 + t;
      if (e < nE) atomicAdd(&hist[dst[e] >> bsh], 1);
    }
    __syncthreads();
    int cnt = hist[t];
    if (cnt > 0) base[t] = atomicAdd(&bcur[t], cnt);  // staging offset, bucket t
    hist[t] = 0;  // reuse as intra-block rank counter
    __syncthreads();
#pragma unroll
    for (int j = 0; j < BS1_TILE / 256; j++) {
      int e = tile + j * 256 + t;
      if (e < nE) {
        int d = dst[e], bk = d >> bsh;
        int r = atomicAdd(&hist[bk], 1);
        stg[(size_t)bk * cap + base[bk] + r] =
            make_uint2((unsigned)src[e], (unsigned)d | ((unsigned)et[e] << 20));
      }
    }
    return;
  }
  int b2 = b - nb1;
  if (b2 < nb_cvt) {
    int i = b2 * 256 + t;
    if (i < n4) {
      float4 v = ((const float4*)emb)[i];
      union { short s[4]; uint2 u; } o;
      o.s[0] = f2bf(v.x); o.s[1] = f2bf(v.y); o.s[2] = f2bf(v.z); o.s[3] = f2bf(v.w);
      ((uint2*)emb_h)[i] = o.u;
      int node = i >> 4, ch = i & 15;  // x0 passthrough (256B/row, full lines)
      *(float4*)(out + (size_t)node * 160 + ch * 4) = v;
    }
  } else if (b2 < nb_cvt + 12) {
    int k = b2 - nb_cvt;
    for (int i = t; i < 4096; i += 256) {
      int d = i >> 6, r = i & 63;
      Bt[k * 4096 + r * 64 + d] = f2bf(Wr[k * 4096 + i]);
    }
  } else {
    int i = (b2 - nb_cvt - 12) * 256 + t;
    const float* W; short* H; short* L; int j;
    if (i < 4096) { W = W10; H = w1h0; L = w1l0; j = i; }
    else if (i < 8192) { W = W20; H = w2h0; L = w2l0; j = i - 4096; }
    else if (i < 10240) { W = W11; H = w1h1; L = w1l1; j = i - 8192; }
    else if (i < 12288) { W = W21; H = w2h1; L = w2l1; j = i - 10240; }
    else return;
    float w = W[j];
    short hi = f2bf(w);
    H[j] = hi;
    L[j] = f2bf(w - bf2f(hi));
  }
}

// proj GEMM (R16-verified, 60us): 128-node blocks, wave = 32 rows x 64 cols
// per relation, 16x16x32 bf16 MFMA (16 MFMA : 8 B-loads per wave-k). proj is
// PLANE-major [k][N][64]: per-block per-k store = 16KB contiguous. Epilogue
// bounces C through a WAVE-PRIVATE LDS tile (stride 72 shorts) -> short8
// 1KB-contiguous stores. No barriers: intra-wave DS ops are in-order.
__global__ __launch_bounds__(256) void k_projm(const short* __restrict__ A,
                                               const short* __restrict__ Bt,
                                               short* __restrict__ proj,
                                               int n_ent) {
  __shared__ unsigned short sh[4][32 * 72];
  int wave = threadIdx.x >> 6, lane = threadIdx.x & 63;
  int quad = lane >> 4, l16 = lane & 15;
  int m0 = blockIdx.x * 128 + wave * 32;
  unsigned short* W = &sh[wave][0];
  short8 a[2][2];
#pragma unroll
  for (int mt = 0; mt < 2; mt++)
#pragma unroll
    for (int kc = 0; kc < 2; kc++) {
      int row = m0 + mt * 16 + l16;
      int rr = row < n_ent ? row : 0;  // clamp; clamped rows never stored
      a[mt][kc] = *(const short8*)(A + (size_t)rr * 64 + kc * 32 + quad * 8);
    }
  for (int k = 0; k < 12; k++) {
    const short* B = Bt + k * 4096;
    short8 b[4][2];
#pragma unroll
    for (int nt = 0; nt < 4; nt++)
#pragma unroll
      for (int kc = 0; kc < 2; kc++)
        b[nt][kc] = *(const short8*)(B + (nt * 16 + l16) * 64 + kc * 32 + quad * 8);
    float4v acc[2][4];
#pragma unroll
    for (int mt = 0; mt < 2; mt++)
#pragma unroll
      for (int nt = 0; nt < 4; nt++)
        acc[mt][nt] = (float4v){0.f, 0.f, 0.f, 0.f};
#pragma unroll
    for (int kc = 0; kc < 2; kc++)
#pragma unroll
      for (int mt = 0; mt < 2; mt++)
#pragma unroll
        for (int nt = 0; nt < 4; nt++)
          acc[mt][nt] = __builtin_amdgcn_mfma_f32_16x16x32_bf16(
              a[mt][kc], b[nt][kc], acc[mt][nt], 0, 0, 0);
    // C layout: col = nt*16+l16, row = mt*16 + quad*4 + r
#pragma unroll
    for (int mt = 0; mt < 2; mt++)
#pragma unroll
      for (int nt = 0; nt < 4; nt++)
#pragma unroll
        for (int r = 0; r < 4; r++) {
          int row = mt * 16 + quad * 4 + r;
          int col = nt * 16 + l16;
          W[row * 72 + col] = (unsigned short)f2bf(acc[mt][nt][r]);
        }
    const size_t plane = (size_t)k * n_ent;
#pragma unroll
    for (int i = 0; i < 4; i++) {
      int row = (lane >> 3) + 8 * i;
      int cs = (lane & 7) * 8;
      short8 v = *(const short8*)(W + row * 72 + cs);
      int node = m0 + row;
      if (node < n_ent)
        *(short8*)(proj + (plane + node) * 64 + cs) = v;
    }
  }
}

// Bucket-sort pass C: one block per bucket. Scans bcur itself (<=256 ints)
// for its CSR base, local LDS histogram over its <=1024 dsts, local scan ->
// per-dst offsets; writes row_ptr AND places edges. Output region
// block-exclusive -> full write combining.
__global__ __launch_bounds__(256) void k_bsort2(const uint2* __restrict__ stg,
                                                const int* __restrict__ bcur,
                                                int* __restrict__ row_ptr,
                                                uint2* __restrict__ csr2,
                                                int n, int bsh, int cap,
                                                int nbuck, int nE) {
  __shared__ int cnt[1024];
  __shared__ int sc[1024];
  __shared__ int bs[256];
  int b = blockIdx.x, t = threadIdx.x;
  // self-scan of bucket counts -> this bucket's CSR base
  int v = (t < nbuck) ? bcur[t] : 0;
  bs[t] = v;
  __syncthreads();
  for (int o = 1; o < 256; o <<= 1) {
    int a = (t >= o) ? bs[t - o] : 0;
    __syncthreads();
    bs[t] += a;
    __syncthreads();
  }
  int gbase = bs[b] - bcur[b];  // exclusive prefix at b
  int lo = b << bsh;
  if (lo > n) lo = n;
  int hi = (b + 1) << bsh;
  if (hi > n) hi = n;
  int w = hi - lo;
#pragma unroll
  for (int j = 0; j < 4; j++) cnt[t + j * 256] = 0;
  __syncthreads();
  int m = bcur[b];
  const uint2* S = stg + (size_t)b * cap;
  for (int p = t; p < m; p += 256)
    atomicAdd(&cnt[(int)(S[p].y & 0xFFFFFu) - lo], 1);
  __syncthreads();
#pragma unroll
  for (int j = 0; j < 4; j++) sc[t + j * 256] = cnt[t + j * 256];
  __syncthreads();
  for (int o = 1; o < 1024; o <<= 1) {
    int a[4];
#pragma unroll
    for (int j = 0; j < 4; j++) {
      int i = t + j * 256;
      a[j] = (i >= o) ? sc[i - o] : 0;
    }
    __syncthreads();
#pragma unroll
    for (int j = 0; j < 4; j++) sc[t + j * 256] += a[j];
    __syncthreads();
  }
#pragma unroll
  for (int j = 0; j < 4; j++) {
    int i = t + j * 256;
    if (i < w) {
      int c0 = gbase + sc[i] - cnt[i];  // exclusive offset for dst lo+i
      row_ptr[lo + i] = c0;
      cnt[i] = c0;  // reuse as global cursor
    }
  }
  if (b == nbuck - 1 && t == 0) row_ptr[n] = nE;
  __syncthreads();
  for (int p = t; p < m; p += 256) {
    uint2 vv = S[p];
    int d = (int)(vv.y & 0xFFFFFu);
    int pos = atomicAdd(&cnt[d - lo], 1);
    csr2[pos] = vv;
  }
}

// Edge scores + exp, walking edges in dst-sorted order (csr2): head gathers
// stream monotonically through each proj plane, tail gathers hit LLC behind
// the stream. ex is written IN PLACE over csr2[e].y. 8 lanes per edge
// (128B rows), 4 edge-batches per wave. proj is PLANE-major [k][N][64].
__global__ __launch_bounds__(256) void k_logits(const short* __restrict__ ps,
                                                const float* __restrict__ rel_emb,
                                                uint2* csr2, int nE, int n_ent) {
  int t = threadIdx.x;
  int lane = t & 63;
  int sub = lane >> 3;        // edge slot within wave (0..7)
  int c8 = (lane & 7) * 8;    // component group base
  int e0 = (blockIdx.x * 4 + (t >> 6)) * 32;
  if (e0 >= nE) return;
  int ku[4];
  short8 tl[4], hd[4];
#pragma unroll
  for (int u = 0; u < 4; u++) {
    int e = e0 + u * 8 + sub;
    int ee = e < nE ? e : nE - 1;
    uint2 c = csr2[ee];
    int s = (int)c.x;
    int d = (int)(c.y & 0xFFFFFu);
    int k = (int)(c.y >> 20);
    ku[u] = k;
    const size_t plane = (size_t)k * n_ent;
    tl[u] = *(const short8*)(ps + (plane + s) * 64 + c8);
    hd[u] = *(const short8*)(ps + (plane + d) * 64 + c8);
  }
  float v[4];
#pragma unroll
  for (int u = 0; u < 4; u++) {
    const float* rp = rel_emb + ku[u] * 64 + c8;
    float4 r0 = *(const float4*)rp;
    float4 r1 = *(const float4*)(rp + 4);
    float rr[8] = {r0.x, r0.y, r0.z, r0.w, r1.x, r1.y, r1.z, r1.w};
    float vv = 0.f;
#pragma unroll
    for (int q = 0; q < 8; q++) {
      float x = bf2f(hd[u][q]) + rr[q];
      // tanh(x) = 1 - 2/(exp2(2*log2e*x)+1); v_exp + v_rcp, no IEEE div
      float tt = __builtin_amdgcn_exp2f(x * (2.f * LOG2E));
      float r = __builtin_amdgcn_rcpf(tt + 1.f);
      float th = fmaf(-2.f, r, 1.f);
      vv = fmaf(bf2f(tl[u][q]), th, vv);
    }
    vv += __shfl_xor(vv, 1);
    vv += __shfl_xor(vv, 2);
    vv += __shfl_xor(vv, 4);
    v[u] = __builtin_amdgcn_exp2f(vv * LOG2E);  // e^vv; logits bounded
  }
  // One edge per lane (32 lanes): edge (u=lane&7, sub). v is uniform across
  // each sub-group of 8 lanes, so the select chain is safe.
  int uu = lane & 7;
  if (uu < 4) {
    float myv = v[0];
    if (uu == 1) myv = v[1];
    if (uu == 2) myv = v[2];
    if (uu == 3) myv = v[3];
    int e = e0 + uu * 8 + sub;
    if (e < nE) csr2[e].y = __float_as_uint(myv);
  }
}

// h_n[n,:] = (sum_j ex_j * x[src_j,:]) / den. Wave per node, lane = col.
// ONE coalesced csr load (lane=entry), shfl broadcast, den wave-reduced.
// Masked 8-wide batches: lanes >= deg hold exv=0 so OOR shfl sources add 0.
__global__ __launch_bounds__(256) void k_agg(const short* __restrict__ xh,
                                             const int* __restrict__ row_ptr,
                                             const uint2* __restrict__ csr,
                                             float* __restrict__ hn, int n_ent) {
  int wave = threadIdx.x >> 6, lane = threadIdx.x & 63;
  int n = blockIdx.x * 4 + wave;
  if (n >= n_ent) return;
  int jb = row_ptr[n], je = row_ptr[n + 1];
  int deg = je - jb;
  if (deg == 0) {
    hn[(size_t)n * 64 + lane] = 0.f;  // no edges: reference h = 0
    return;
  }
  uint2 c = (lane < deg) ? csr[jb + lane] : make_uint2(0u, 0u);
  int sidx = (int)c.x;
  float exv = (lane < deg) ? __uint_as_float(c.y) : 0.f;
  float den = exv;
#pragma unroll
  for (int o = 32; o; o >>= 1) den += __shfl_xor(den, o);
  int m = deg < 64 ? deg : 64;
  float acc = 0.f;
  for (int j = 0; j < m; j += 8) {
    int s0 = __shfl(sidx, j), s1 = __shfl(sidx, j + 1);
    int s2 = __shfl(sidx, j + 2), s3 = __shfl(sidx, j + 3);
    int s4 = __shfl(sidx, j + 4), s5 = __shfl(sidx, j + 5);
    int s6 = __shfl(sidx, j + 6), s7 = __shfl(sidx, j + 7);
    float e0 = __shfl(exv, j), e1 = __shfl(exv, j + 1);
    float e2 = __shfl(exv, j + 2), e3 = __shfl(exv, j + 3);
    float e4 = __shfl(exv, j + 4), e5 = __shfl(exv, j + 5);
    float e6 = __shfl(exv, j + 6), e7 = __shfl(exv, j + 7);
    short g0 = xh[(size_t)s0 * 64 + lane];
    short g1 = xh[(size_t)s1 * 64 + lane];
    short g2 = xh[(size_t)s2 * 64 + lane];
    short g3 = xh[(size_t)s3 * 64 + lane];
    short g4 = xh[(size_t)s4 * 64 + lane];
    short g5 = xh[(size_t)s5 * 64 + lane];
    short g6 = xh[(size_t)s6 * 64 + lane];
    short g7 = xh[(size_t)s7 * 64 + lane];
    acc = fmaf(e0, bf2f(g0), acc); acc = fmaf(e1, bf2f(g1), acc);
    acc = fmaf(e2, bf2f(g2), acc); acc = fmaf(e3, bf2f(g3), acc);
    acc = fmaf(e4, bf2f(g4), acc); acc = fmaf(e5, bf2f(g5), acc);
    acc = fmaf(e6, bf2f(g6), acc); acc = fmaf(e7, bf2f(g7), acc);
  }
  if (deg > 64) {  // rare (E/N ~ 10); broadcast loads, den stays uniform
    for (int jj = jb + 64; jj < je; jj++) {
      uint2 cc = csr[jj];
      float ee = __uint_as_float(cc.y);
      den += ee;
      acc = fmaf(ee, bf2f(xh[(size_t)cc.x * 64 + lane]), acc);
    }
  }
  hn[(size_t)n * 64 + lane] = acc / den;
}

// y = lrelu((x+h)W1^T+b1) + lrelu((x*h)W2^T+b2) via MFMA.
// Split-bf16 GEMM (3 terms) keeps f32-level accuracy. Block = 4 waves x 32
// nodes = 128 nodes. Weights (hi/lo) staged once to LDS (stride 72 shorts).
// EPILOGUE: after a barrier the weight LDS is dead -> reused as per-wave f32
// y-tiles (stride 66/34, 2-way banks max); lane reads a row float4 -> full-
// line stores (y 256B/row, x1 256B/row, x1h 128B/row). No shfl needed for
// the bf16 pack. x0 passthrough lives in k_prep now.
template <int OD, bool FIRST>
__global__ __launch_bounds__(256) void k_upmfma(const float* __restrict__ x,
                                                const float* __restrict__ hn,
                                                const short* __restrict__ g1h,
                                                const short* __restrict__ g1l,
                                                const short* __restrict__ g2h,
                                                const short* __restrict__ g2l,
                                                const float* __restrict__ b1,
                                                const float* __restrict__ b2,
                                                float* __restrict__ out,
                                                float* __restrict__ x_next,
                                                short* __restrict__ xh_next,
                                                int n_ent) {
  constexpr int NT = OD / 16;
  constexpr int S = (OD == 64) ? 66 : 34;  // f32 tile stride: 4S%32==8 -> 2-way
  __shared__ short wbuf[4 * OD * 72];      // weights, then reused as y-tiles
  short* w1h = wbuf;
  short* w1l = wbuf + OD * 72;
  short* w2h = wbuf + 2 * OD * 72;
  short* w2l = wbuf + 3 * OD * 72;
  int t = threadIdx.x;
  for (int i = t; i < OD * 16; i += 256) {  // uint2 = 4 shorts per slot
    int o = i >> 4, dq = (i & 15) * 4;
    *(uint2*)(w1h + o * 72 + dq) = *(const uint2*)(g1h + o * 64 + dq);
    *(uint2*)(w1l + o * 72 + dq) = *(const uint2*)(g1l + o * 64 + dq);
    *(uint2*)(w2h + o * 72 + dq) = *(const uint2*)(g2h + o * 64 + dq);
    *(uint2*)(w2l + o * 72 + dq) = *(const uint2*)(g2l + o * 64 + dq);
  }
  int wave = t >> 6, lane = t & 63;
  int quad = lane >> 4, l16 = lane & 15;
  int m0 = blockIdx.x * 128 + wave * 32;
  float4v accA[2][NT], accM[2][NT];
#pragma unroll
  for (int mt = 0; mt < 2; mt++)
#pragma unroll
    for (int nt = 0; nt < NT; nt++) {
      accA[mt][nt] = (float4v){0.f, 0.f, 0.f, 0.f};
      accM[mt][nt] = (float4v){0.f, 0.f, 0.f, 0.f};
    }
  __syncthreads();
#pragma unroll
  for (int kc = 0; kc < 2; kc++) {
    short8 ah_add[2], al_add[2], ah_mul[2], al_mul[2];
#pragma unroll
    for (int mt = 0; mt < 2; mt++) {
      int row = m0 + mt * 16 + l16;
      int rr = row < n_ent ? row : 0;  // clamp; clamped rows never stored
      const float* xp = x + (size_t)rr * 64 + kc * 32 + quad * 8;
      const float* hp = hn + (size_t)rr * 64 + kc * 32 + quad * 8;
      float4 xa = *(const float4*)xp;
      float4 xb = *(const float4*)(xp + 4);
      float4 ha = *(const float4*)hp;
      float4 hb = *(const float4*)(hp + 4);
      float xs[8] = {xa.x, xa.y, xa.z, xa.w, xb.x, xb.y, xb.z, xb.w};
      float hs[8] = {ha.x, ha.y, ha.z, ha.w, hb.x, hb.y, hb.z, hb.w};
#pragma unroll
      for (int q = 0; q < 8; q++) {
        float s = xs[q] + hs[q];
        short shi = f2bf(s);
        ah_add[mt][q] = shi;
        al_add[mt][q] = f2bf(s - bf2f(shi));
        float p = xs[q] * hs[q];
        short phi = f2bf(p);
        ah_mul[mt][q] = phi;
        al_mul[mt][q] = f2bf(p - bf2f(phi));
      }
    }
#pragma unroll
    for (int nt = 0; nt < NT; nt++) {
      int boff = (nt * 16 + l16) * 72 + kc * 32 + quad * 8;
      short8 b1h = *(const short8*)(w1h + boff);
      short8 b1l = *(const short8*)(w1l + boff);
      short8 b2h = *(const short8*)(w2h + boff);
      short8 b2l = *(const short8*)(w2l + boff);
#pragma unroll
      for (int mt = 0; mt < 2; mt++) {
        accA[mt][nt] = __builtin_amdgcn_mfma_f32_16x16x32_bf16(
            ah_add[mt], b1h, accA[mt][nt], 0, 0, 0);
        accA[mt][nt] = __builtin_amdgcn_mfma_f32_16x16x32_bf16(
            al_add[mt], b1h, accA[mt][nt], 0, 0, 0);
        accA[mt][nt] = __builtin_amdgcn_mfma_f32_16x16x32_bf16(
            ah_add[mt], b1l, accA[mt][nt], 0, 0, 0);
        accM[mt][nt] = __builtin_amdgcn_mfma_f32_16x16x32_bf16(
            ah_mul[mt], b2h, accM[mt][nt], 0, 0, 0);
        accM[mt][nt] = __builtin_amdgcn_mfma_f32_16x16x32_bf16(
            al_mul[mt], b2h, accM[mt][nt], 0, 0, 0);
        accM[mt][nt] = __builtin_amdgcn_mfma_f32_16x16x32_bf16(
            ah_mul[mt], b2l, accM[mt][nt], 0, 0, 0);
      }
    }
  }
  // ---- epilogue: weights are dead after this barrier; reuse LDS as y-tile
  __syncthreads();
  float* yt = (float*)wbuf + wave * 32 * S;
  // C layout: col = nt*16+l16, row = mt*16 + quad*4 + r
#pragma unroll
  for (int nt = 0; nt < NT; nt++) {
    int col = nt * 16 + l16;
    float bb1 = b1[col], bb2 = b2[col];
#pragma unroll
    for (int mt = 0; mt < 2; mt++) {
#pragma unroll
      for (int r = 0; r < 4; r++) {
        float aa = accA[mt][nt][r] + bb1;
        float mm = accM[mt][nt][r] + bb2;
        aa = aa > 0.f ? aa : 0.01f * aa;
        mm = mm > 0.f ? mm : 0.01f * mm;
        yt[(mt * 16 + quad * 4 + r) * S + col] = aa + mm;
      }
    }
  }
  // wave-private tile; intra-wave DS ordering HW-guaranteed (no barrier)
  constexpr int LPR = OD / 4;    // lanes per row
  constexpr int RPI = 64 / LPR;  // rows per iteration
#pragma unroll
  for (int i = 0; i < 32 / RPI; i++) {
    int rloc = i * RPI + lane / LPR;
    int c4 = (lane % LPR) * 4;
    float4 v = *(const float4*)(yt + rloc * S + c4);
    int node = m0 + rloc;
    if (node < n_ent) {
      if constexpr (FIRST) {
        *(float4*)(out + (size_t)node * 160 + 64 + c4) = v;
        *(float4*)(x_next + (size_t)node * 64 + c4) = v;
        unsigned p0 = (unsigned)(unsigned short)f2bf(v.x) |
                      ((unsigned)(unsigned short)f2bf(v.y) << 16);
        unsigned p1 = (unsigned)(unsigned short)f2bf(v.z) |
                      ((unsigned)(unsigned short)f2bf(v.w) << 16);
        *(uint2*)(xh_next + (size_t)node * 64 + c4) = make_uint2(p0, p1);
      } else {
        *(float4*)(out + (size_t)node * 160 + 128 + c4) = v;
      }
    }
  }
}

extern "C" void kernel_launch(void* const* d_in, const int* in_sizes, int n_in,
                              void* d_out, int out_size, void* d_ws, size_t ws_size,
                              hipStream_t stream) {
  const float* emb = (const float*)d_in[0];
  const float* rel = (const float*)d_in[1];
  const float* Wr = (const float*)d_in[2];
  const float* W10w = (const float*)d_in[3];
  const float* W10b = (const float*)d_in[4];
  const float* W20w = (const float*)d_in[5];
  const float* W20b = (const float*)d_in[6];
  const float* W11w = (const float*)d_in[7];
  const float* W11b = (const float*)d_in[8];
  const float* W21w = (const float*)d_in[9];
  const float* W21b = (const float*)d_in[10];
  const int* src = (const int*)d_in[11];
  const int* dst = (const int*)d_in[12];
  const int* et = (const int*)d_in[13];
  int N = in_sizes[0] / 64;
  int E = in_sizes[11];
  float* out = (float*)d_out;

  int bsh = 9;
  while (((N + (1 << bsh) - 1) >> bsh) > 256) bsh++;  // nbuck <= 256
  int nbuck = (N + (1 << bsh) - 1) >> bsh;
  int cap = ((E / nbuck) * 3 / 2 + 1024 + 255) / 256 * 256;  // ~50 sigma margin

  char* p = (char*)d_ws;
  auto alloc = [&](size_t bytes) -> char* {
    char* r = p;
    p += (bytes + 255) / 256 * 256;
    return r;
  };
  short* proj = (short*)alloc((size_t)N * 768 * 2);
  uint2* csr2 = (uint2*)alloc((size_t)E * 8);  // final CSR {src, dst|et} -> {src, ex}
  uint2* stg = (uint2*)alloc((size_t)nbuck * cap * 8);  // per-bucket staging
  int* row_ptr = (int*)alloc((size_t)(N + 1) * 4);
  int* bcur = (int*)alloc(1024);               // bucket staging cursors
  float* hn = (float*)alloc((size_t)N * 64 * 4);
  float* x1 = (float*)alloc((size_t)N * 64 * 4);
  short* emb_h = (short*)alloc(((size_t)N + 128) * 64 * 2);  // bf16 emb, padded
  short* x1h = (short*)alloc(((size_t)N + 128) * 64 * 2);    // bf16 x1
  short* Bt = (short*)alloc((size_t)12 * 4096 * 2);          // bf16 W_r^T
  short* w1h0 = (short*)alloc(4096 * 2);                     // layer-weight hi/lo
  short* w1l0 = (short*)alloc(4096 * 2);
  short* w2h0 = (short*)alloc(4096 * 2);
  short* w2l0 = (short*)alloc(4096 * 2);
  short* w1h1 = (short*)alloc(2048 * 2);
  short* w1l1 = (short*)alloc(2048 * 2);
  short* w2h1 = (short*)alloc(2048 * 2);
  short* w2l1 = (short*)alloc(2048 * 2);

  int n4 = N * 16;
  int nb_cvt = (n4 + 255) / 256;
  int nb1 = (E + BS1_TILE - 1) / BS1_TILE;  // bsort1 blocks (merged into prep)

  hipMemsetAsync(bcur, 0, 1024, stream);
  k_prep<<<nb1 + nb_cvt + 60, 256, 0, stream>>>(
      emb, emb_h, out, Wr, Bt, W10w, W20w, W11w, W21w,
      w1h0, w1l0, w2h0, w2l0, w1h1, w1l1, w2h1, w2l1,
      src, dst, et, bcur, stg, E, bsh, cap, nb1, nb_cvt, n4);
  k_projm<<<(N + 127) / 128, 256, 0, stream>>>(emb_h, Bt, proj, N);
  k_bsort2<<<nbuck, 256, 0, stream>>>(stg, bcur, row_ptr, csr2, N, bsh, cap, nbuck, E);
  k_logits<<<(E + 127) / 128, 256, 0, stream>>>(proj, rel, csr2, E, N);
  k_agg<<<(N + 3) / 4, 256, 0, stream>>>(emb_h, row_ptr, csr2, hn, N);
  k_upmfma<64, true><<<(N + 127) / 128, 256, 0, stream>>>(
      emb, hn, w1h0, w1l0, w2h0, w2l0, W10b, W20b, out, x1, x1h, N);
  k_agg<<<(N + 3) / 4, 256, 0, stream>>>(x1h, row_ptr, csr2, hn, N);
  k_upmfma<32, false><<<(N + 127) / 128, 256, 0, stream>>>(
      x1, hn, w1h1, w1l1, w2h1, w2l1, W11b, W21b, out, nullptr, nullptr, N);
}

// Round 13
// 338.189 us; speedup vs baseline: 1.2316x; 1.1187x over previous
//
#include <hip/hip_runtime.h>
#include <hip/hip_bf16.h>
#include <math.h>

// ---------------------------------------------------------------------------
// KGAT on MI355X.
//   N = 100000 entities, R = 12 relations, D = 64, E = 1e6 edges.
//   proj[k,n,r] = sum_d emb[n,d] * W_r[k,d,r]   -> bf16 MFMA GEMM (PLANE-major)
//   logits[e]   = sum_r proj[et,src,r] * tanh(proj[et,dst,r] + rel[et,r])
//   att         = edge_softmax(logits, by dst)  (unnormalized exp; logits bounded)
//   layer(x):   h = segsum(x[src]*att -> dst); y = lrelu((x+h)W1^T+b1)+lrelu((x*h)W2^T+b2)
//   out = [x0 | x1 | x2]  row stride 160 (f32)
// R20: projm stable at 60us / 2.65 TB/s / occ 22% -- per-wave issue/ILP
//     bound (R17 showed smaller waves regress; 64-row waves never tested).
//     (a) projm retiled to 64-row waves (4 waves x 64 rows = 256 nodes/block,
//         grid 391): B-reuse x2 and store ILP x2 per wave at constant total
//         wave count. 32 MFMA : 8 B-loads : 8 stores per wave per k.
//     (b) bsort2 (10us, 196 short latency blocks, depends only on prep like
//         the GEMM) APPENDED to the same dispatch: its blocks fill the GEMM's
//         round-2 slack (391 blocks = 1.53/CU). Short+few minority blocks --
//         not R15's long-pinning failure mode.
// ---------------------------------------------------------------------------

typedef __attribute__((ext_vector_type(8))) short short8;   // 8 bf16 (4 VGPR)
typedef __attribute__((ext_vector_type(4))) float float4v;  // MFMA acc

__device__ __forceinline__ short f2bf(float f) {
  __hip_bfloat16 h = __float2bfloat16(f);
  return *(short*)&h;
}
__device__ __forceinline__ float bf2f(short s) {
  return __uint_as_float(((unsigned)(unsigned short)s) << 16);
}

#define LOG2E 1.4426950408889634f
#define BS1_TILE 2048

// Merged prep: [0,nb1) bucket-sort pass B (latency-bound, starts at t=0) |
// then emb f32->bf16 + x0 passthrough to out | 12 blocks W_r transpose+cvt |
// 48 blocks layer-weight hi/lo bf16 split.
__global__ void k_prep(const float* __restrict__ emb, short* __restrict__ emb_h,
                       float* __restrict__ out,
                       const float* __restrict__ Wr, short* __restrict__ Bt,
                       const float* __restrict__ W10, const float* __restrict__ W20,
                       const float* __restrict__ W11, const float* __restrict__ W21,
                       short* __restrict__ w1h0, short* __restrict__ w1l0,
                       short* __restrict__ w2h0, short* __restrict__ w2l0,
                       short* __restrict__ w1h1, short* __restrict__ w1l1,
                       short* __restrict__ w2h1, short* __restrict__ w2l1,
                       const int* __restrict__ src, const int* __restrict__ dst,
                       const int* __restrict__ et, int* __restrict__ bcur,
                       uint2* __restrict__ stg, int nE, int bsh, int cap,
                       int nb1, int nb_cvt, int n4) {
  __shared__ int hist[256];
  __shared__ int base[256];
  int b = blockIdx.x, t = threadIdx.x;
  if (b < nb1) {
    // ---- bsort1 block b: BS1_TILE-edge tile, LDS hist over dst>>bsh
    // buckets, one atomicAdd per (block,bucket) reserves a staging run.
    hist[t] = 0;
    __syncthreads();
    int tile = b * BS1_TILE;
#pragma unroll
    for (int j = 0; j < BS1_TILE / 256; j++) {
      int e = tile + j * 256 + t;
      if (e < nE) atomicAdd(&hist[dst[e] >> bsh], 1);
    }
    __syncthreads();
    int cnt = hist[t];
    if (cnt > 0) base[t] = atomicAdd(&bcur[t], cnt);  // staging offset, bucket t
    hist[t] = 0;  // reuse as intra-block rank counter
    __syncthreads();
#pragma unroll
    for (int j = 0; j < BS1_TILE / 256; j++) {
      int e = tile + j * 256 + t;
      if (e < nE) {
        int d = dst[e], bk = d >> bsh;
        int r = atomicAdd(&hist[bk], 1);
        stg[(size_t)bk * cap + base[bk] + r] =
            make_uint2((unsigned)src[e], (unsigned)d | ((unsigned)et[e] << 20));
      }
    }
    return;
  }
  int b2 = b - nb1;
  if (b2 < nb_cvt) {
    int i = b2 * 256 + t;
    if (i < n4) {
      float4 v = ((const float4*)emb)[i];
      union { short s[4]; uint2 u; } o;
      o.s[0] = f2bf(v.x); o.s[1] = f2bf(v.y); o.s[2] = f2bf(v.z); o.s[3] = f2bf(v.w);
      ((uint2*)emb_h)[i] = o.u;
      int node = i >> 4, ch = i & 15;  // x0 passthrough (256B/row, full lines)
      *(float4*)(out + (size_t)node * 160 + ch * 4) = v;
    }
  } else if (b2 < nb_cvt + 12) {
    int k = b2 - nb_cvt;
    for (int i = t; i < 4096; i += 256) {
      int d = i >> 6, r = i & 63;
      Bt[k * 4096 + r * 64 + d] = f2bf(Wr[k * 4096 + i]);
    }
  } else {
    int i = (b2 - nb_cvt - 12) * 256 + t;
    const float* W; short* H; short* L; int j;
    if (i < 4096) { W = W10; H = w1h0; L = w1l0; j = i; }
    else if (i < 8192) { W = W20; H = w2h0; L = w2l0; j = i - 4096; }
    else if (i < 10240) { W = W11; H = w1h1; L = w1l1; j = i - 8192; }
    else if (i < 12288) { W = W21; H = w2h1; L = w2l1; j = i - 10240; }
    else return;
    float w = W[j];
    short hi = f2bf(w);
    H[j] = hi;
    L[j] = f2bf(w - bf2f(hi));
  }
}

// Merged proj GEMM + bucket-sort pass C (both depend only on k_prep).
// GEMM blocks [0, nbg): 4 waves x 64 rows = 256 nodes/block. Per wave per k:
//   32 MFMA : 8 B-frag loads : 8 short8 stores (2x B-reuse and store ILP of
//   the 32-row form). proj PLANE-major [k][N][64]; LDS-bounce epilogue
//   (stride 72, wave-private, no barriers) -> 1KB-contiguous stores.
// bsort2 blocks [nbg, nbg+nbuck): one per bucket; self-scan bcur -> CSR base,
//   LDS hist+scan over <=1024 dsts, writes row_ptr AND places edges.
__global__ __launch_bounds__(256) void k_projb2(const short* __restrict__ A,
                                                const short* __restrict__ Bt,
                                                short* __restrict__ proj,
                                                int n_ent,
                                                const uint2* __restrict__ stg,
                                                const int* __restrict__ bcur,
                                                int* __restrict__ row_ptr,
                                                uint2* __restrict__ csr2,
                                                int nbg, int bsh, int cap,
                                                int nbuck, int nE) {
  __shared__ char smem[4 * 64 * 72 * 2];  // 36864B: GEMM tiles / bsort2 tables
  int bid = blockIdx.x, t = threadIdx.x;
  if (bid >= nbg) {
    // ---- bsort2 bucket b ----
    int b = bid - nbg;
    int* cnt = (int*)smem;        // [1024]
    int* sc = cnt + 1024;         // [1024]
    int* bs = sc + 1024;          // [256]
    int v = (t < nbuck) ? bcur[t] : 0;
    bs[t] = v;
    __syncthreads();
    for (int o = 1; o < 256; o <<= 1) {
      int a = (t >= o) ? bs[t - o] : 0;
      __syncthreads();
      bs[t] += a;
      __syncthreads();
    }
    int gbase = bs[b] - bcur[b];  // exclusive prefix at b
    int n = n_ent;
    int lo = b << bsh;
    if (lo > n) lo = n;
    int hi = (b + 1) << bsh;
    if (hi > n) hi = n;
    int w = hi - lo;
#pragma unroll
    for (int j = 0; j < 4; j++) cnt[t + j * 256] = 0;
    __syncthreads();
    int m = bcur[b];
    const uint2* S = stg + (size_t)b * cap;
    for (int p = t; p < m; p += 256)
      atomicAdd(&cnt[(int)(S[p].y & 0xFFFFFu) - lo], 1);
    __syncthreads();
#pragma unroll
    for (int j = 0; j < 4; j++) sc[t + j * 256] = cnt[t + j * 256];
    __syncthreads();
    for (int o = 1; o < 1024; o <<= 1) {
      int a[4];
#pragma unroll
      for (int j = 0; j < 4; j++) {
        int i = t + j * 256;
        a[j] = (i >= o) ? sc[i - o] : 0;
      }
      __syncthreads();
#pragma unroll
      for (int j = 0; j < 4; j++) sc[t + j * 256] += a[j];
      __syncthreads();
    }
#pragma unroll
    for (int j = 0; j < 4; j++) {
      int i = t + j * 256;
      if (i < w) {
        int c0 = gbase + sc[i] - cnt[i];  // exclusive offset for dst lo+i
        row_ptr[lo + i] = c0;
        cnt[i] = c0;  // reuse as global cursor
      }
    }
    if (b == nbuck - 1 && t == 0) row_ptr[n] = nE;
    __syncthreads();
    for (int p = t; p < m; p += 256) {
      uint2 vv = S[p];
      int d = (int)(vv.y & 0xFFFFFu);
      int pos = atomicAdd(&cnt[d - lo], 1);
      csr2[pos] = vv;
    }
    return;
  }
  // ---- GEMM block ----
  int wave = t >> 6, lane = t & 63;
  int quad = lane >> 4, l16 = lane & 15;
  int m0 = bid * 256 + wave * 64;
  unsigned short* W = (unsigned short*)smem + wave * 64 * 72;
  short8 a[4][2];
#pragma unroll
  for (int mt = 0; mt < 4; mt++)
#pragma unroll
    for (int kc = 0; kc < 2; kc++) {
      int row = m0 + mt * 16 + l16;
      int rr = row < n_ent ? row : 0;  // clamp; clamped rows never stored
      a[mt][kc] = *(const short8*)(A + (size_t)rr * 64 + kc * 32 + quad * 8);
    }
  for (int k = 0; k < 12; k++) {
    const short* B = Bt + k * 4096;
    short8 b[4][2];
#pragma unroll
    for (int nt = 0; nt < 4; nt++)
#pragma unroll
      for (int kc = 0; kc < 2; kc++)
        b[nt][kc] = *(const short8*)(B + (nt * 16 + l16) * 64 + kc * 32 + quad * 8);
    float4v acc[4][4];
#pragma unroll
    for (int mt = 0; mt < 4; mt++)
#pragma unroll
      for (int nt = 0; nt < 4; nt++)
        acc[mt][nt] = (float4v){0.f, 0.f, 0.f, 0.f};
#pragma unroll
    for (int kc = 0; kc < 2; kc++)
#pragma unroll
      for (int mt = 0; mt < 4; mt++)
#pragma unroll
        for (int nt = 0; nt < 4; nt++)
          acc[mt][nt] = __builtin_amdgcn_mfma_f32_16x16x32_bf16(
              a[mt][kc], b[nt][kc], acc[mt][nt], 0, 0, 0);
    // C layout: col = nt*16+l16, row = mt*16 + quad*4 + r
#pragma unroll
    for (int mt = 0; mt < 4; mt++)
#pragma unroll
      for (int nt = 0; nt < 4; nt++)
#pragma unroll
        for (int r = 0; r < 4; r++) {
          int row = mt * 16 + quad * 4 + r;
          int col = nt * 16 + l16;
          W[row * 72 + col] = (unsigned short)f2bf(acc[mt][nt][r]);
        }
    const size_t plane = (size_t)k * n_ent;
#pragma unroll
    for (int i = 0; i < 8; i++) {
      int row = (lane >> 3) + 8 * i;
      int cs = (lane & 7) * 8;
      short8 v = *(const short8*)(W + row * 72 + cs);
      int node = m0 + row;
      if (node < n_ent)
        *(short8*)(proj + (plane + node) * 64 + cs) = v;
    }
  }
}

// Edge scores + exp, walking edges in dst-sorted order (csr2): head gathers
// stream monotonically through each proj plane, tail gathers hit LLC behind
// the stream. ex is written IN PLACE over csr2[e].y. 8 lanes per edge
// (128B rows), 4 edge-batches per wave. proj is PLANE-major [k][N][64].
__global__ __launch_bounds__(256) void k_logits(const short* __restrict__ ps,
                                                const float* __restrict__ rel_emb,
                                                uint2* csr2, int nE, int n_ent) {
  int t = threadIdx.x;
  int lane = t & 63;
  int sub = lane >> 3;        // edge slot within wave (0..7)
  int c8 = (lane & 7) * 8;    // component group base
  int e0 = (blockIdx.x * 4 + (t >> 6)) * 32;
  if (e0 >= nE) return;
  int ku[4];
  short8 tl[4], hd[4];
#pragma unroll
  for (int u = 0; u < 4; u++) {
    int e = e0 + u * 8 + sub;
    int ee = e < nE ? e : nE - 1;
    uint2 c = csr2[ee];
    int s = (int)c.x;
    int d = (int)(c.y & 0xFFFFFu);
    int k = (int)(c.y >> 20);
    ku[u] = k;
    const size_t plane = (size_t)k * n_ent;
    tl[u] = *(const short8*)(ps + (plane + s) * 64 + c8);
    hd[u] = *(const short8*)(ps + (plane + d) * 64 + c8);
  }
  float v[4];
#pragma unroll
  for (int u = 0; u < 4; u++) {
    const float* rp = rel_emb + ku[u] * 64 + c8;
    float4 r0 = *(const float4*)rp;
    float4 r1 = *(const float4*)(rp + 4);
    float rr[8] = {r0.x, r0.y, r0.z, r0.w, r1.x, r1.y, r1.z, r1.w};
    float vv = 0.f;
#pragma unroll
    for (int q = 0; q < 8; q++) {
      float x = bf2f(hd[u][q]) + rr[q];
      // tanh(x) = 1 - 2/(exp2(2*log2e*x)+1); v_exp + v_rcp, no IEEE div
      float tt = __builtin_amdgcn_exp2f(x * (2.f * LOG2E));
      float r = __builtin_amdgcn_rcpf(tt + 1.f);
      float th = fmaf(-2.f, r, 1.f);
      vv = fmaf(bf2f(tl[u][q]), th, vv);
    }
    vv += __shfl_xor(vv, 1);
    vv += __shfl_xor(vv, 2);
    vv += __shfl_xor(vv, 4);
    v[u] = __builtin_amdgcn_exp2f(vv * LOG2E);  // e^vv; logits bounded
  }
  // One edge per lane (32 lanes): edge (u=lane&7, sub). v is uniform across
  // each sub-group of 8 lanes, so the select chain is safe.
  int uu = lane & 7;
  if (uu < 4) {
    float myv = v[0];
    if (uu == 1) myv = v[1];
    if (uu == 2) myv = v[2];
    if (uu == 3) myv = v[3];
    int e = e0 + uu * 8 + sub;
    if (e < nE) csr2[e].y = __float_as_uint(myv);
  }
}

// h_n[n,:] = (sum_j ex_j * x[src_j,:]) / den. Wave per node, lane = col.
// ONE coalesced csr load (lane=entry), shfl broadcast, den wave-reduced.
// Masked 8-wide batches: lanes >= deg hold exv=0 so OOR shfl sources add 0.
__global__ __launch_bounds__(256) void k_agg(const short* __restrict__ xh,
                                             const int* __restrict__ row_ptr,
                                             const uint2* __restrict__ csr,
                                             float* __restrict__ hn, int n_ent) {
  int wave = threadIdx.x >> 6, lane = threadIdx.x & 63;
  int n = blockIdx.x * 4 + wave;
  if (n >= n_ent) return;
  int jb = row_ptr[n], je = row_ptr[n + 1];
  int deg = je - jb;
  if (deg == 0) {
    hn[(size_t)n * 64 + lane] = 0.f;  // no edges: reference h = 0
    return;
  }
  uint2 c = (lane < deg) ? csr[jb + lane] : make_uint2(0u, 0u);
  int sidx = (int)c.x;
  float exv = (lane < deg) ? __uint_as_float(c.y) : 0.f;
  float den = exv;
#pragma unroll
  for (int o = 32; o; o >>= 1) den += __shfl_xor(den, o);
  int m = deg < 64 ? deg : 64;
  float acc = 0.f;
  for (int j = 0; j < m; j += 8) {
    int s0 = __shfl(sidx, j), s1 = __shfl(sidx, j + 1);
    int s2 = __shfl(sidx, j + 2), s3 = __shfl(sidx, j + 3);
    int s4 = __shfl(sidx, j + 4), s5 = __shfl(sidx, j + 5);
    int s6 = __shfl(sidx, j + 6), s7 = __shfl(sidx, j + 7);
    float e0 = __shfl(exv, j), e1 = __shfl(exv, j + 1);
    float e2 = __shfl(exv, j + 2), e3 = __shfl(exv, j + 3);
    float e4 = __shfl(exv, j + 4), e5 = __shfl(exv, j + 5);
    float e6 = __shfl(exv, j + 6), e7 = __shfl(exv, j + 7);
    short g0 = xh[(size_t)s0 * 64 + lane];
    short g1 = xh[(size_t)s1 * 64 + lane];
    short g2 = xh[(size_t)s2 * 64 + lane];
    short g3 = xh[(size_t)s3 * 64 + lane];
    short g4 = xh[(size_t)s4 * 64 + lane];
    short g5 = xh[(size_t)s5 * 64 + lane];
    short g6 = xh[(size_t)s6 * 64 + lane];
    short g7 = xh[(size_t)s7 * 64 + lane];
    acc = fmaf(e0, bf2f(g0), acc); acc = fmaf(e1, bf2f(g1), acc);
    acc = fmaf(e2, bf2f(g2), acc); acc = fmaf(e3, bf2f(g3), acc);
    acc = fmaf(e4, bf2f(g4), acc); acc = fmaf(e5, bf2f(g5), acc);
    acc = fmaf(e6, bf2f(g6), acc); acc = fmaf(e7, bf2f(g7), acc);
  }
  if (deg > 64) {  // rare (E/N ~ 10); broadcast loads, den stays uniform
    for (int jj = jb + 64; jj < je; jj++) {
      uint2 cc = csr[jj];
      float ee = __uint_as_float(cc.y);
      den += ee;
      acc = fmaf(ee, bf2f(xh[(size_t)cc.x * 64 + lane]), acc);
    }
  }
  hn[(size_t)n * 64 + lane] = acc / den;
}

// y = lrelu((x+h)W1^T+b1) + lrelu((x*h)W2^T+b2) via MFMA.
// Split-bf16 GEMM (3 terms) keeps f32-level accuracy. Block = 4 waves x 32
// nodes = 128 nodes. Weights (hi/lo) staged once to LDS (stride 72 shorts).
// EPILOGUE: after a barrier the weight LDS is dead -> reused as per-wave f32
// y-tiles (stride 66/34, 2-way banks max); lane reads a row float4 -> full-
// line stores (y 256B/row, x1 256B/row, x1h 128B/row). No shfl needed for
// the bf16 pack. x0 passthrough lives in k_prep.
template <int OD, bool FIRST>
__global__ __launch_bounds__(256) void k_upmfma(const float* __restrict__ x,
                                                const float* __restrict__ hn,
                                                const short* __restrict__ g1h,
                                                const short* __restrict__ g1l,
                                                const short* __restrict__ g2h,
                                                const short* __restrict__ g2l,
                                                const float* __restrict__ b1,
                                                const float* __restrict__ b2,
                                                float* __restrict__ out,
                                                float* __restrict__ x_next,
                                                short* __restrict__ xh_next,
                                                int n_ent) {
  constexpr int NT = OD / 16;
  constexpr int S = (OD == 64) ? 66 : 34;  // f32 tile stride: 4S%32==8 -> 2-way
  __shared__ short wbuf[4 * OD * 72];      // weights, then reused as y-tiles
  short* w1h = wbuf;
  short* w1l = wbuf + OD * 72;
  short* w2h = wbuf + 2 * OD * 72;
  short* w2l = wbuf + 3 * OD * 72;
  int t = threadIdx.x;
  for (int i = t; i < OD * 16; i += 256) {  // uint2 = 4 shorts per slot
    int o = i >> 4, dq = (i & 15) * 4;
    *(uint2*)(w1h + o * 72 + dq) = *(const uint2*)(g1h + o * 64 + dq);
    *(uint2*)(w1l + o * 72 + dq) = *(const uint2*)(g1l + o * 64 + dq);
    *(uint2*)(w2h + o * 72 + dq) = *(const uint2*)(g2h + o * 64 + dq);
    *(uint2*)(w2l + o * 72 + dq) = *(const uint2*)(g2l + o * 64 + dq);
  }
  int wave = t >> 6, lane = t & 63;
  int quad = lane >> 4, l16 = lane & 15;
  int m0 = blockIdx.x * 128 + wave * 32;
  float4v accA[2][NT], accM[2][NT];
#pragma unroll
  for (int mt = 0; mt < 2; mt++)
#pragma unroll
    for (int nt = 0; nt < NT; nt++) {
      accA[mt][nt] = (float4v){0.f, 0.f, 0.f, 0.f};
      accM[mt][nt] = (float4v){0.f, 0.f, 0.f, 0.f};
    }
  __syncthreads();
#pragma unroll
  for (int kc = 0; kc < 2; kc++) {
    short8 ah_add[2], al_add[2], ah_mul[2], al_mul[2];
#pragma unroll
    for (int mt = 0; mt < 2; mt++) {
      int row = m0 + mt * 16 + l16;
      int rr = row < n_ent ? row : 0;  // clamp; clamped rows never stored
      const float* xp = x + (size_t)rr * 64 + kc * 32 + quad * 8;
      const float* hp = hn + (size_t)rr * 64 + kc * 32 + quad * 8;
      float4 xa = *(const float4*)xp;
      float4 xb = *(const float4*)(xp + 4);
      float4 ha = *(const float4*)hp;
      float4 hb = *(const float4*)(hp + 4);
      float xs[8] = {xa.x, xa.y, xa.z, xa.w, xb.x, xb.y, xb.z, xb.w};
      float hs[8] = {ha.x, ha.y, ha.z, ha.w, hb.x, hb.y, hb.z, hb.w};
#pragma unroll
      for (int q = 0; q < 8; q++) {
        float s = xs[q] + hs[q];
        short shi = f2bf(s);
        ah_add[mt][q] = shi;
        al_add[mt][q] = f2bf(s - bf2f(shi));
        float p = xs[q] * hs[q];
        short phi = f2bf(p);
        ah_mul[mt][q] = phi;
        al_mul[mt][q] = f2bf(p - bf2f(phi));
      }
    }
#pragma unroll
    for (int nt = 0; nt < NT; nt++) {
      int boff = (nt * 16 + l16) * 72 + kc * 32 + quad * 8;
      short8 b1h = *(const short8*)(w1h + boff);
      short8 b1l = *(const short8*)(w1l + boff);
      short8 b2h = *(const short8*)(w2h + boff);
      short8 b2l = *(const short8*)(w2l + boff);
#pragma unroll
      for (int mt = 0; mt < 2; mt++) {
        accA[mt][nt] = __builtin_amdgcn_mfma_f32_16x16x32_bf16(
            ah_add[mt], b1h, accA[mt][nt], 0, 0, 0);
        accA[mt][nt] = __builtin_amdgcn_mfma_f32_16x16x32_bf16(
            al_add[mt], b1h, accA[mt][nt], 0, 0, 0);
        accA[mt][nt] = __builtin_amdgcn_mfma_f32_16x16x32_bf16(
            ah_add[mt], b1l, accA[mt][nt], 0, 0, 0);
        accM[mt][nt] = __builtin_amdgcn_mfma_f32_16x16x32_bf16(
            ah_mul[mt], b2h, accM[mt][nt], 0, 0, 0);
        accM[mt][nt] = __builtin_amdgcn_mfma_f32_16x16x32_bf16(
            al_mul[mt], b2h, accM[mt][nt], 0, 0, 0);
        accM[mt][nt] = __builtin_amdgcn_mfma_f32_16x16x32_bf16(
            ah_mul[mt], b2l, accM[mt][nt], 0, 0, 0);
      }
    }
  }
  // ---- epilogue: weights are dead after this barrier; reuse LDS as y-tile
  __syncthreads();
  float* yt = (float*)wbuf + wave * 32 * S;
  // C layout: col = nt*16+l16, row = mt*16 + quad*4 + r
#pragma unroll
  for (int nt = 0; nt < NT; nt++) {
    int col = nt * 16 + l16;
    float bb1 = b1[col], bb2 = b2[col];
#pragma unroll
    for (int mt = 0; mt < 2; mt++) {
#pragma unroll
      for (int r = 0; r < 4; r++) {
        float aa = accA[mt][nt][r] + bb1;
        float mm = accM[mt][nt][r] + bb2;
        aa = aa > 0.f ? aa : 0.01f * aa;
        mm = mm > 0.f ? mm : 0.01f * mm;
        yt[(mt * 16 + quad * 4 + r) * S + col] = aa + mm;
      }
    }
  }
  // wave-private tile; intra-wave DS ordering HW-guaranteed (no barrier)
  constexpr int LPR = OD / 4;    // lanes per row
  constexpr int RPI = 64 / LPR;  // rows per iteration
#pragma unroll
  for (int i = 0; i < 32 / RPI; i++) {
    int rloc = i * RPI + lane / LPR;
    int c4 = (lane % LPR) * 4;
    float4 v = *(const float4*)(yt + rloc * S + c4);
    int node = m0 + rloc;
    if (node < n_ent) {
      if constexpr (FIRST) {
        *(float4*)(out + (size_t)node * 160 + 64 + c4) = v;
        *(float4*)(x_next + (size_t)node * 64 + c4) = v;
        unsigned p0 = (unsigned)(unsigned short)f2bf(v.x) |
                      ((unsigned)(unsigned short)f2bf(v.y) << 16);
        unsigned p1 = (unsigned)(unsigned short)f2bf(v.z) |
                      ((unsigned)(unsigned short)f2bf(v.w) << 16);
        *(uint2*)(xh_next + (size_t)node * 64 + c4) = make_uint2(p0, p1);
      } else {
        *(float4*)(out + (size_t)node * 160 + 128 + c4) = v;
      }
    }
  }
}

extern "C" void kernel_launch(void* const* d_in, const int* in_sizes, int n_in,
                              void* d_out, int out_size, void* d_ws, size_t ws_size,
                              hipStream_t stream) {
  const float* emb = (const float*)d_in[0];
  const float* rel = (const float*)d_in[1];
  const float* Wr = (const float*)d_in[2];
  const float* W10w = (const float*)d_in[3];
  const float* W10b = (const float*)d_in[4];
  const float* W20w = (const float*)d_in[5];
  const float* W20b = (const float*)d_in[6];
  const float* W11w = (const float*)d_in[7];
  const float* W11b = (const float*)d_in[8];
  const float* W21w = (const float*)d_in[9];
  const float* W21b = (const float*)d_in[10];
  const int* src = (const int*)d_in[11];
  const int* dst = (const int*)d_in[12];
  const int* et = (const int*)d_in[13];
  int N = in_sizes[0] / 64;
  int E = in_sizes[11];
  float* out = (float*)d_out;

  int bsh = 9;
  while (((N + (1 << bsh) - 1) >> bsh) > 256) bsh++;  // nbuck <= 256
  int nbuck = (N + (1 << bsh) - 1) >> bsh;
  int cap = ((E / nbuck) * 3 / 2 + 1024 + 255) / 256 * 256;  // ~50 sigma margin

  char* p = (char*)d_ws;
  auto alloc = [&](size_t bytes) -> char* {
    char* r = p;
    p += (bytes + 255) / 256 * 256;
    return r;
  };
  short* proj = (short*)alloc((size_t)N * 768 * 2);
  uint2* csr2 = (uint2*)alloc((size_t)E * 8);  // final CSR {src, dst|et} -> {src, ex}
  uint2* stg = (uint2*)alloc((size_t)nbuck * cap * 8);  // per-bucket staging
  int* row_ptr = (int*)alloc((size_t)(N + 1) * 4);
  int* bcur = (int*)alloc(1024);               // bucket staging cursors
  float* hn = (float*)alloc((size_t)N * 64 * 4);
  float* x1 = (float*)alloc((size_t)N * 64 * 4);
  short* emb_h = (short*)alloc(((size_t)N + 256) * 64 * 2);  // bf16 emb, padded
  short* x1h = (short*)alloc(((size_t)N + 256) * 64 * 2);    // bf16 x1
  short* Bt = (short*)alloc((size_t)12 * 4096 * 2);          // bf16 W_r^T
  short* w1h0 = (short*)alloc(4096 * 2);                     // layer-weight hi/lo
  short* w1l0 = (short*)alloc(4096 * 2);
  short* w2h0 = (short*)alloc(4096 * 2);
  short* w2l0 = (short*)alloc(4096 * 2);
  short* w1h1 = (short*)alloc(2048 * 2);
  short* w1l1 = (short*)alloc(2048 * 2);
  short* w2h1 = (short*)alloc(2048 * 2);
  short* w2l1 = (short*)alloc(2048 * 2);

  int n4 = N * 16;
  int nb_cvt = (n4 + 255) / 256;
  int nb1 = (E + BS1_TILE - 1) / BS1_TILE;  // bsort1 blocks (merged into prep)
  int nbg = (N + 255) / 256;                // GEMM blocks (256 nodes each)

  hipMemsetAsync(bcur, 0, 1024, stream);
  k_prep<<<nb1 + nb_cvt + 60, 256, 0, stream>>>(
      emb, emb_h, out, Wr, Bt, W10w, W20w, W11w, W21w,
      w1h0, w1l0, w2h0, w2l0, w1h1, w1l1, w2h1, w2l1,
      src, dst, et, bcur, stg, E, bsh, cap, nb1, nb_cvt, n4);
  k_projb2<<<nbg + nbuck, 256, 0, stream>>>(
      emb_h, Bt, proj, N, stg, bcur, row_ptr, csr2, nbg, bsh, cap, nbuck, E);
  k_logits<<<(E + 127) / 128, 256, 0, stream>>>(proj, rel, csr2, E, N);
  k_agg<<<(N + 3) / 4, 256, 0, stream>>>(emb_h, row_ptr, csr2, hn, N);
  k_upmfma<64, true><<<(N + 127) / 128, 256, 0, stream>>>(
      emb, hn, w1h0, w1l0, w2h0, w2l0, W10b, W20b, out, x1, x1h, N);
  k_agg<<<(N + 3) / 4, 256, 0, stream>>>(x1h, row_ptr, csr2, hn, N);
  k_upmfma<32, false><<<(N + 127) / 128, 256, 0, stream>>>(
      x1, hn, w1h1, w1l1, w2h1, w2l1, W11b, W21b, out, nullptr, nullptr, N);
}

// Round 14
// 335.176 us; speedup vs baseline: 1.2427x; 1.0090x over previous
//
#include <hip/hip_runtime.h>
#include <hip/hip_bf16.h>
#include <math.h>

// ---------------------------------------------------------------------------
// KGAT on MI355X.
//   N = 100000 entities, R = 12 relations, D = 64, E = 1e6 edges.
//   proj[k,n,r] = sum_d emb[n,d] * W_r[k,d,r]   -> bf16 MFMA GEMM (PLANE-major)
//   logits[e]   = sum_r proj[et,src,r] * tanh(proj[et,dst,r] + rel[et,r])
//   att         = edge_softmax(logits, by dst)  (unnormalized exp; logits bounded)
//   layer(x):   h = segsum(x[src]*att -> dst); y = lrelu((x+h)W1^T+b1)+lrelu((x*h)W2^T+b2)
//   out = [x0 | x1 | x2]  row stride 160 (f32)
// R21: k_logits (54us) is latency-bound mixed-gather (FETCH 107MB ~=
//     compulsory, 2.2 TB/s, VALU 42%, occ 48%, VGPR only 36):
//     (a) 8 edge-batches/wave (64 edges, 16 row-gathers in flight, ~100 VGPR)
//         -- double the MLP using the huge register headroom.
//     (b) bijective XCD-chunked blockIdx swizzle (T1/m204): consecutive
//         dst-sorted edge blocks share head lines; chunking gives each XCD's
//         private L2 a contiguous head-stream window (default round-robin
//         re-fetches each head line in up to 8 XCDs).
// ---------------------------------------------------------------------------

typedef __attribute__((ext_vector_type(8))) short short8;   // 8 bf16 (4 VGPR)
typedef __attribute__((ext_vector_type(4))) float float4v;  // MFMA acc

__device__ __forceinline__ short f2bf(float f) {
  __hip_bfloat16 h = __float2bfloat16(f);
  return *(short*)&h;
}
__device__ __forceinline__ float bf2f(short s) {
  return __uint_as_float(((unsigned)(unsigned short)s) << 16);
}

#define LOG2E 1.4426950408889634f
#define BS1_TILE 2048

// Merged prep: [0,nb1) bucket-sort pass B (latency-bound, starts at t=0) |
// then emb f32->bf16 + x0 passthrough to out | 12 blocks W_r transpose+cvt |
// 48 blocks layer-weight hi/lo bf16 split.
__global__ void k_prep(const float* __restrict__ emb, short* __restrict__ emb_h,
                       float* __restrict__ out,
                       const float* __restrict__ Wr, short* __restrict__ Bt,
                       const float* __restrict__ W10, const float* __restrict__ W20,
                       const float* __restrict__ W11, const float* __restrict__ W21,
                       short* __restrict__ w1h0, short* __restrict__ w1l0,
                       short* __restrict__ w2h0, short* __restrict__ w2l0,
                       short* __restrict__ w1h1, short* __restrict__ w1l1,
                       short* __restrict__ w2h1, short* __restrict__ w2l1,
                       const int* __restrict__ src, const int* __restrict__ dst,
                       const int* __restrict__ et, int* __restrict__ bcur,
                       uint2* __restrict__ stg, int nE, int bsh, int cap,
                       int nb1, int nb_cvt, int n4) {
  __shared__ int hist[256];
  __shared__ int base[256];
  int b = blockIdx.x, t = threadIdx.x;
  if (b < nb1) {
    // ---- bsort1 block b: BS1_TILE-edge tile, LDS hist over dst>>bsh
    // buckets, one atomicAdd per (block,bucket) reserves a staging run.
    hist[t] = 0;
    __syncthreads();
    int tile = b * BS1_TILE;
#pragma unroll
    for (int j = 0; j < BS1_TILE / 256; j++) {
      int e = tile + j * 256 + t;
      if (e < nE) atomicAdd(&hist[dst[e] >> bsh], 1);
    }
    __syncthreads();
    int cnt = hist[t];
    if (cnt > 0) base[t] = atomicAdd(&bcur[t], cnt);  // staging offset, bucket t
    hist[t] = 0;  // reuse as intra-block rank counter
    __syncthreads();
#pragma unroll
    for (int j = 0; j < BS1_TILE / 256; j++) {
      int e = tile + j * 256 + t;
      if (e < nE) {
        int d = dst[e], bk = d >> bsh;
        int r = atomicAdd(&hist[bk], 1);
        stg[(size_t)bk * cap + base[bk] + r] =
            make_uint2((unsigned)src[e], (unsigned)d | ((unsigned)et[e] << 20));
      }
    }
    return;
  }
  int b2 = b - nb1;
  if (b2 < nb_cvt) {
    int i = b2 * 256 + t;
    if (i < n4) {
      float4 v = ((const float4*)emb)[i];
      union { short s[4]; uint2 u; } o;
      o.s[0] = f2bf(v.x); o.s[1] = f2bf(v.y); o.s[2] = f2bf(v.z); o.s[3] = f2bf(v.w);
      ((uint2*)emb_h)[i] = o.u;
      int node = i >> 4, ch = i & 15;  // x0 passthrough (256B/row, full lines)
      *(float4*)(out + (size_t)node * 160 + ch * 4) = v;
    }
  } else if (b2 < nb_cvt + 12) {
    int k = b2 - nb_cvt;
    for (int i = t; i < 4096; i += 256) {
      int d = i >> 6, r = i & 63;
      Bt[k * 4096 + r * 64 + d] = f2bf(Wr[k * 4096 + i]);
    }
  } else {
    int i = (b2 - nb_cvt - 12) * 256 + t;
    const float* W; short* H; short* L; int j;
    if (i < 4096) { W = W10; H = w1h0; L = w1l0; j = i; }
    else if (i < 8192) { W = W20; H = w2h0; L = w2l0; j = i - 4096; }
    else if (i < 10240) { W = W11; H = w1h1; L = w1l1; j = i - 8192; }
    else if (i < 12288) { W = W21; H = w2h1; L = w2l1; j = i - 10240; }
    else return;
    float w = W[j];
    short hi = f2bf(w);
    H[j] = hi;
    L[j] = f2bf(w - bf2f(hi));
  }
}

// Merged proj GEMM + bucket-sort pass C (both depend only on k_prep).
// GEMM blocks [0, nbg): 4 waves x 64 rows = 256 nodes/block. Per wave per k:
//   32 MFMA : 8 B-frag loads : 8 short8 stores. proj PLANE-major [k][N][64];
//   LDS-bounce epilogue (stride 72, wave-private, no barriers).
// bsort2 blocks [nbg, nbg+nbuck): one per bucket; self-scan bcur -> CSR base,
//   LDS hist+scan over <=1024 dsts, writes row_ptr AND places edges.
__global__ __launch_bounds__(256) void k_projb2(const short* __restrict__ A,
                                                const short* __restrict__ Bt,
                                                short* __restrict__ proj,
                                                int n_ent,
                                                const uint2* __restrict__ stg,
                                                const int* __restrict__ bcur,
                                                int* __restrict__ row_ptr,
                                                uint2* __restrict__ csr2,
                                                int nbg, int bsh, int cap,
                                                int nbuck, int nE) {
  __shared__ char smem[4 * 64 * 72 * 2];  // 36864B: GEMM tiles / bsort2 tables
  int bid = blockIdx.x, t = threadIdx.x;
  if (bid >= nbg) {
    // ---- bsort2 bucket b ----
    int b = bid - nbg;
    int* cnt = (int*)smem;        // [1024]
    int* sc = cnt + 1024;         // [1024]
    int* bs = sc + 1024;          // [256]
    int v = (t < nbuck) ? bcur[t] : 0;
    bs[t] = v;
    __syncthreads();
    for (int o = 1; o < 256; o <<= 1) {
      int a = (t >= o) ? bs[t - o] : 0;
      __syncthreads();
      bs[t] += a;
      __syncthreads();
    }
    int gbase = bs[b] - bcur[b];  // exclusive prefix at b
    int n = n_ent;
    int lo = b << bsh;
    if (lo > n) lo = n;
    int hi = (b + 1) << bsh;
    if (hi > n) hi = n;
    int w = hi - lo;
#pragma unroll
    for (int j = 0; j < 4; j++) cnt[t + j * 256] = 0;
    __syncthreads();
    int m = bcur[b];
    const uint2* S = stg + (size_t)b * cap;
    for (int p = t; p < m; p += 256)
      atomicAdd(&cnt[(int)(S[p].y & 0xFFFFFu) - lo], 1);
    __syncthreads();
#pragma unroll
    for (int j = 0; j < 4; j++) sc[t + j * 256] = cnt[t + j * 256];
    __syncthreads();
    for (int o = 1; o < 1024; o <<= 1) {
      int a[4];
#pragma unroll
      for (int j = 0; j < 4; j++) {
        int i = t + j * 256;
        a[j] = (i >= o) ? sc[i - o] : 0;
      }
      __syncthreads();
#pragma unroll
      for (int j = 0; j < 4; j++) sc[t + j * 256] += a[j];
      __syncthreads();
    }
#pragma unroll
    for (int j = 0; j < 4; j++) {
      int i = t + j * 256;
      if (i < w) {
        int c0 = gbase + sc[i] - cnt[i];  // exclusive offset for dst lo+i
        row_ptr[lo + i] = c0;
        cnt[i] = c0;  // reuse as global cursor
      }
    }
    if (b == nbuck - 1 && t == 0) row_ptr[n] = nE;
    __syncthreads();
    for (int p = t; p < m; p += 256) {
      uint2 vv = S[p];
      int d = (int)(vv.y & 0xFFFFFu);
      int pos = atomicAdd(&cnt[d - lo], 1);
      csr2[pos] = vv;
    }
    return;
  }
  // ---- GEMM block ----
  int wave = t >> 6, lane = t & 63;
  int quad = lane >> 4, l16 = lane & 15;
  int m0 = bid * 256 + wave * 64;
  unsigned short* W = (unsigned short*)smem + wave * 64 * 72;
  short8 a[4][2];
#pragma unroll
  for (int mt = 0; mt < 4; mt++)
#pragma unroll
    for (int kc = 0; kc < 2; kc++) {
      int row = m0 + mt * 16 + l16;
      int rr = row < n_ent ? row : 0;  // clamp; clamped rows never stored
      a[mt][kc] = *(const short8*)(A + (size_t)rr * 64 + kc * 32 + quad * 8);
    }
  for (int k = 0; k < 12; k++) {
    const short* B = Bt + k * 4096;
    short8 b[4][2];
#pragma unroll
    for (int nt = 0; nt < 4; nt++)
#pragma unroll
      for (int kc = 0; kc < 2; kc++)
        b[nt][kc] = *(const short8*)(B + (nt * 16 + l16) * 64 + kc * 32 + quad * 8);
    float4v acc[4][4];
#pragma unroll
    for (int mt = 0; mt < 4; mt++)
#pragma unroll
      for (int nt = 0; nt < 4; nt++)
        acc[mt][nt] = (float4v){0.f, 0.f, 0.f, 0.f};
#pragma unroll
    for (int kc = 0; kc < 2; kc++)
#pragma unroll
      for (int mt = 0; mt < 4; mt++)
#pragma unroll
        for (int nt = 0; nt < 4; nt++)
          acc[mt][nt] = __builtin_amdgcn_mfma_f32_16x16x32_bf16(
              a[mt][kc], b[nt][kc], acc[mt][nt], 0, 0, 0);
    // C layout: col = nt*16+l16, row = mt*16 + quad*4 + r
#pragma unroll
    for (int mt = 0; mt < 4; mt++)
#pragma unroll
      for (int nt = 0; nt < 4; nt++)
#pragma unroll
        for (int r = 0; r < 4; r++) {
          int row = mt * 16 + quad * 4 + r;
          int col = nt * 16 + l16;
          W[row * 72 + col] = (unsigned short)f2bf(acc[mt][nt][r]);
        }
    const size_t plane = (size_t)k * n_ent;
#pragma unroll
    for (int i = 0; i < 8; i++) {
      int row = (lane >> 3) + 8 * i;
      int cs = (lane & 7) * 8;
      short8 v = *(const short8*)(W + row * 72 + cs);
      int node = m0 + row;
      if (node < n_ent)
        *(short8*)(proj + (plane + node) * 64 + cs) = v;
    }
  }
}

// Edge scores + exp, walking edges in dst-sorted order (csr2): head gathers
// stream monotonically through each proj plane, tail gathers hit LLC behind
// the stream. ex is written IN PLACE over csr2[e].y. 8 lanes per edge
// (128B rows), EIGHT edge-batches per wave (16 row-gathers in flight).
// Blocks XCD-chunk-swizzled (bijective) so each XCD's private L2 serves a
// contiguous head-stream window. proj is PLANE-major [k][N][64].
__global__ __launch_bounds__(256) void k_logits(const short* __restrict__ ps,
                                                const float* __restrict__ rel_emb,
                                                uint2* csr2, int nE, int n_ent,
                                                int nwg) {
  int bid = blockIdx.x;
  int q = nwg >> 3, r8 = nwg & 7;
  int xcd = bid & 7, idx = bid >> 3;
  int swz = (xcd < r8 ? xcd * (q + 1) : r8 * (q + 1) + (xcd - r8) * q) + idx;
  int t = threadIdx.x;
  int lane = t & 63;
  int sub = lane >> 3;        // edge slot within batch (0..7)
  int c8 = (lane & 7) * 8;    // component group base
  int e0 = (swz * 4 + (t >> 6)) * 64;
  if (e0 >= nE) return;
  int ku[8];
  short8 tl[8], hd[8];
#pragma unroll
  for (int u = 0; u < 8; u++) {
    int e = e0 + u * 8 + sub;
    int ee = e < nE ? e : nE - 1;
    uint2 c = csr2[ee];
    int s = (int)c.x;
    int d = (int)(c.y & 0xFFFFFu);
    int k = (int)(c.y >> 20);
    ku[u] = k;
    const size_t plane = (size_t)k * n_ent;
    tl[u] = *(const short8*)(ps + (plane + s) * 64 + c8);
    hd[u] = *(const short8*)(ps + (plane + d) * 64 + c8);
  }
  float v[8];
#pragma unroll
  for (int u = 0; u < 8; u++) {
    const float* rp = rel_emb + ku[u] * 64 + c8;
    float4 r0 = *(const float4*)rp;
    float4 r1 = *(const float4*)(rp + 4);
    float rr[8] = {r0.x, r0.y, r0.z, r0.w, r1.x, r1.y, r1.z, r1.w};
    float vv = 0.f;
#pragma unroll
    for (int qq = 0; qq < 8; qq++) {
      float x = bf2f(hd[u][qq]) + rr[qq];
      // tanh(x) = 1 - 2/(exp2(2*log2e*x)+1); v_exp + v_rcp, no IEEE div
      float tt = __builtin_amdgcn_exp2f(x * (2.f * LOG2E));
      float rc = __builtin_amdgcn_rcpf(tt + 1.f);
      float th = fmaf(-2.f, rc, 1.f);
      vv = fmaf(bf2f(tl[u][qq]), th, vv);
    }
    vv += __shfl_xor(vv, 1);
    vv += __shfl_xor(vv, 2);
    vv += __shfl_xor(vv, 4);
    v[u] = __builtin_amdgcn_exp2f(vv * LOG2E);  // e^vv; logits bounded
  }
  // One edge per lane (64 lanes): lane l -> edge (u = l&7, sub' = l>>3).
  // v[u] is uniform across each consecutive-8 lane group, so the select
  // chain is safe.
  int uu = lane & 7;
  float myv = v[0];
#pragma unroll
  for (int u = 1; u < 8; u++)
    if (uu == u) myv = v[u];
  int e = e0 + uu * 8 + sub;
  if (e < nE) csr2[e].y = __float_as_uint(myv);
}

// h_n[n,:] = (sum_j ex_j * x[src_j,:]) / den. Wave per node, lane = col.
// ONE coalesced csr load (lane=entry), shfl broadcast, den wave-reduced.
// Masked 8-wide batches: lanes >= deg hold exv=0 so OOR shfl sources add 0.
__global__ __launch_bounds__(256) void k_agg(const short* __restrict__ xh,
                                             const int* __restrict__ row_ptr,
                                             const uint2* __restrict__ csr,
                                             float* __restrict__ hn, int n_ent) {
  int wave = threadIdx.x >> 6, lane = threadIdx.x & 63;
  int n = blockIdx.x * 4 + wave;
  if (n >= n_ent) return;
  int jb = row_ptr[n], je = row_ptr[n + 1];
  int deg = je - jb;
  if (deg == 0) {
    hn[(size_t)n * 64 + lane] = 0.f;  // no edges: reference h = 0
    return;
  }
  uint2 c = (lane < deg) ? csr[jb + lane] : make_uint2(0u, 0u);
  int sidx = (int)c.x;
  float exv = (lane < deg) ? __uint_as_float(c.y) : 0.f;
  float den = exv;
#pragma unroll
  for (int o = 32; o; o >>= 1) den += __shfl_xor(den, o);
  int m = deg < 64 ? deg : 64;
  float acc = 0.f;
  for (int j = 0; j < m; j += 8) {
    int s0 = __shfl(sidx, j), s1 = __shfl(sidx, j + 1);
    int s2 = __shfl(sidx, j + 2), s3 = __shfl(sidx, j + 3);
    int s4 = __shfl(sidx, j + 4), s5 = __shfl(sidx, j + 5);
    int s6 = __shfl(sidx, j + 6), s7 = __shfl(sidx, j + 7);
    float e0 = __shfl(exv, j), e1 = __shfl(exv, j + 1);
    float e2 = __shfl(exv, j + 2), e3 = __shfl(exv, j + 3);
    float e4 = __shfl(exv, j + 4), e5 = __shfl(exv, j + 5);
    float e6 = __shfl(exv, j + 6), e7 = __shfl(exv, j + 7);
    short g0 = xh[(size_t)s0 * 64 + lane];
    short g1 = xh[(size_t)s1 * 64 + lane];
    short g2 = xh[(size_t)s2 * 64 + lane];
    short g3 = xh[(size_t)s3 * 64 + lane];
    short g4 = xh[(size_t)s4 * 64 + lane];
    short g5 = xh[(size_t)s5 * 64 + lane];
    short g6 = xh[(size_t)s6 * 64 + lane];
    short g7 = xh[(size_t)s7 * 64 + lane];
    acc = fmaf(e0, bf2f(g0), acc); acc = fmaf(e1, bf2f(g1), acc);
    acc = fmaf(e2, bf2f(g2), acc); acc = fmaf(e3, bf2f(g3), acc);
    acc = fmaf(e4, bf2f(g4), acc); acc = fmaf(e5, bf2f(g5), acc);
    acc = fmaf(e6, bf2f(g6), acc); acc = fmaf(e7, bf2f(g7), acc);
  }
  if (deg > 64) {  // rare (E/N ~ 10); broadcast loads, den stays uniform
    for (int jj = jb + 64; jj < je; jj++) {
      uint2 cc = csr[jj];
      float ee = __uint_as_float(cc.y);
      den += ee;
      acc = fmaf(ee, bf2f(xh[(size_t)cc.x * 64 + lane]), acc);
    }
  }
  hn[(size_t)n * 64 + lane] = acc / den;
}

// y = lrelu((x+h)W1^T+b1) + lrelu((x*h)W2^T+b2) via MFMA.
// Split-bf16 GEMM (3 terms) keeps f32-level accuracy. Block = 4 waves x 32
// nodes = 128 nodes. Weights (hi/lo) staged once to LDS (stride 72 shorts).
// EPILOGUE: after a barrier the weight LDS is dead -> reused as per-wave f32
// y-tiles (stride 66/34, 2-way banks max); lane reads a row float4 -> full-
// line stores (y 256B/row, x1 256B/row, x1h 128B/row). No shfl needed for
// the bf16 pack. x0 passthrough lives in k_prep.
template <int OD, bool FIRST>
__global__ __launch_bounds__(256) void k_upmfma(const float* __restrict__ x,
                                                const float* __restrict__ hn,
                                                const short* __restrict__ g1h,
                                                const short* __restrict__ g1l,
                                                const short* __restrict__ g2h,
                                                const short* __restrict__ g2l,
                                                const float* __restrict__ b1,
                                                const float* __restrict__ b2,
                                                float* __restrict__ out,
                                                float* __restrict__ x_next,
                                                short* __restrict__ xh_next,
                                                int n_ent) {
  constexpr int NT = OD / 16;
  constexpr int S = (OD == 64) ? 66 : 34;  // f32 tile stride: 4S%32==8 -> 2-way
  __shared__ short wbuf[4 * OD * 72];      // weights, then reused as y-tiles
  short* w1h = wbuf;
  short* w1l = wbuf + OD * 72;
  short* w2h = wbuf + 2 * OD * 72;
  short* w2l = wbuf + 3 * OD * 72;
  int t = threadIdx.x;
  for (int i = t; i < OD * 16; i += 256) {  // uint2 = 4 shorts per slot
    int o = i >> 4, dq = (i & 15) * 4;
    *(uint2*)(w1h + o * 72 + dq) = *(const uint2*)(g1h + o * 64 + dq);
    *(uint2*)(w1l + o * 72 + dq) = *(const uint2*)(g1l + o * 64 + dq);
    *(uint2*)(w2h + o * 72 + dq) = *(const uint2*)(g2h + o * 64 + dq);
    *(uint2*)(w2l + o * 72 + dq) = *(const uint2*)(g2l + o * 64 + dq);
  }
  int wave = t >> 6, lane = t & 63;
  int quad = lane >> 4, l16 = lane & 15;
  int m0 = blockIdx.x * 128 + wave * 32;
  float4v accA[2][NT], accM[2][NT];
#pragma unroll
  for (int mt = 0; mt < 2; mt++)
#pragma unroll
    for (int nt = 0; nt < NT; nt++) {
      accA[mt][nt] = (float4v){0.f, 0.f, 0.f, 0.f};
      accM[mt][nt] = (float4v){0.f, 0.f, 0.f, 0.f};
    }
  __syncthreads();
#pragma unroll
  for (int kc = 0; kc < 2; kc++) {
    short8 ah_add[2], al_add[2], ah_mul[2], al_mul[2];
#pragma unroll
    for (int mt = 0; mt < 2; mt++) {
      int row = m0 + mt * 16 + l16;
      int rr = row < n_ent ? row : 0;  // clamp; clamped rows never stored
      const float* xp = x + (size_t)rr * 64 + kc * 32 + quad * 8;
      const float* hp = hn + (size_t)rr * 64 + kc * 32 + quad * 8;
      float4 xa = *(const float4*)xp;
      float4 xb = *(const float4*)(xp + 4);
      float4 ha = *(const float4*)hp;
      float4 hb = *(const float4*)(hp + 4);
      float xs[8] = {xa.x, xa.y, xa.z, xa.w, xb.x, xb.y, xb.z, xb.w};
      float hs[8] = {ha.x, ha.y, ha.z, ha.w, hb.x, hb.y, hb.z, hb.w};
#pragma unroll
      for (int qq = 0; qq < 8; qq++) {
        float s = xs[qq] + hs[qq];
        short shi = f2bf(s);
        ah_add[mt][qq] = shi;
        al_add[mt][qq] = f2bf(s - bf2f(shi));
        float p = xs[qq] * hs[qq];
        short phi = f2bf(p);
        ah_mul[mt][qq] = phi;
        al_mul[mt][qq] = f2bf(p - bf2f(phi));
      }
    }
#pragma unroll
    for (int nt = 0; nt < NT; nt++) {
      int boff = (nt * 16 + l16) * 72 + kc * 32 + quad * 8;
      short8 b1h = *(const short8*)(w1h + boff);
      short8 b1l = *(const short8*)(w1l + boff);
      short8 b2h = *(const short8*)(w2h + boff);
      short8 b2l = *(const short8*)(w2l + boff);
#pragma unroll
      for (int mt = 0; mt < 2; mt++) {
        accA[mt][nt] = __builtin_amdgcn_mfma_f32_16x16x32_bf16(
            ah_add[mt], b1h, accA[mt][nt], 0, 0, 0);
        accA[mt][nt] = __builtin_amdgcn_mfma_f32_16x16x32_bf16(
            al_add[mt], b1h, accA[mt][nt], 0, 0, 0);
        accA[mt][nt] = __builtin_amdgcn_mfma_f32_16x16x32_bf16(
            ah_add[mt], b1l, accA[mt][nt], 0, 0, 0);
        accM[mt][nt] = __builtin_amdgcn_mfma_f32_16x16x32_bf16(
            ah_mul[mt], b2h, accM[mt][nt], 0, 0, 0);
        accM[mt][nt] = __builtin_amdgcn_mfma_f32_16x16x32_bf16(
            al_mul[mt], b2h, accM[mt][nt], 0, 0, 0);
        accM[mt][nt] = __builtin_amdgcn_mfma_f32_16x16x32_bf16(
            ah_mul[mt], b2l, accM[mt][nt], 0, 0, 0);
      }
    }
  }
  // ---- epilogue: weights are dead after this barrier; reuse LDS as y-tile
  __syncthreads();
  float* yt = (float*)wbuf + wave * 32 * S;
  // C layout: col = nt*16+l16, row = mt*16 + quad*4 + r
#pragma unroll
  for (int nt = 0; nt < NT; nt++) {
    int col = nt * 16 + l16;
    float bb1 = b1[col], bb2 = b2[col];
#pragma unroll
    for (int mt = 0; mt < 2; mt++) {
#pragma unroll
      for (int r = 0; r < 4; r++) {
        float aa = accA[mt][nt][r] + bb1;
        float mm = accM[mt][nt][r] + bb2;
        aa = aa > 0.f ? aa : 0.01f * aa;
        mm = mm > 0.f ? mm : 0.01f * mm;
        yt[(mt * 16 + quad * 4 + r) * S + col] = aa + mm;
      }
    }
  }
  // wave-private tile; intra-wave DS ordering HW-guaranteed (no barrier)
  constexpr int LPR = OD / 4;    // lanes per row
  constexpr int RPI = 64 / LPR;  // rows per iteration
#pragma unroll
  for (int i = 0; i < 32 / RPI; i++) {
    int rloc = i * RPI + lane / LPR;
    int c4 = (lane % LPR) * 4;
    float4 v = *(const float4*)(yt + rloc * S + c4);
    int node = m0 + rloc;
    if (node < n_ent) {
      if constexpr (FIRST) {
        *(float4*)(out + (size_t)node * 160 + 64 + c4) = v;
        *(float4*)(x_next + (size_t)node * 64 + c4) = v;
        unsigned p0 = (unsigned)(unsigned short)f2bf(v.x) |
                      ((unsigned)(unsigned short)f2bf(v.y) << 16);
        unsigned p1 = (unsigned)(unsigned short)f2bf(v.z) |
                      ((unsigned)(unsigned short)f2bf(v.w) << 16);
        *(uint2*)(xh_next + (size_t)node * 64 + c4) = make_uint2(p0, p1);
      } else {
        *(float4*)(out + (size_t)node * 160 + 128 + c4) = v;
      }
    }
  }
}

extern "C" void kernel_launch(void* const* d_in, const int* in_sizes, int n_in,
                              void* d_out, int out_size, void* d_ws, size_t ws_size,
                              hipStream_t stream) {
  const float* emb = (const float*)d_in[0];
  const float* rel = (const float*)d_in[1];
  const float* Wr = (const float*)d_in[2];
  const float* W10w = (const float*)d_in[3];
  const float* W10b = (const float*)d_in[4];
  const float* W20w = (const float*)d_in[5];
  const float* W20b = (const float*)d_in[6];
  const float* W11w = (const float*)d_in[7];
  const float* W11b = (const float*)d_in[8];
  const float* W21w = (const float*)d_in[9];
  const float* W21b = (const float*)d_in[10];
  const int* src = (const int*)d_in[11];
  const int* dst = (const int*)d_in[12];
  const int* et = (const int*)d_in[13];
  int N = in_sizes[0] / 64;
  int E = in_sizes[11];
  float* out = (float*)d_out;

  int bsh = 9;
  while (((N + (1 << bsh) - 1) >> bsh) > 256) bsh++;  // nbuck <= 256
  int nbuck = (N + (1 << bsh) - 1) >> bsh;
  int cap = ((E / nbuck) * 3 / 2 + 1024 + 255) / 256 * 256;  // ~50 sigma margin

  char* p = (char*)d_ws;
  auto alloc = [&](size_t bytes) -> char* {
    char* r = p;
    p += (bytes + 255) / 256 * 256;
    return r;
  };
  short* proj = (short*)alloc((size_t)N * 768 * 2);
  uint2* csr2 = (uint2*)alloc((size_t)E * 8);  // final CSR {src, dst|et} -> {src, ex}
  uint2* stg = (uint2*)alloc((size_t)nbuck * cap * 8);  // per-bucket staging
  int* row_ptr = (int*)alloc((size_t)(N + 1) * 4);
  int* bcur = (int*)alloc(1024);               // bucket staging cursors
  float* hn = (float*)alloc((size_t)N * 64 * 4);
  float* x1 = (float*)alloc((size_t)N * 64 * 4);
  short* emb_h = (short*)alloc(((size_t)N + 256) * 64 * 2);  // bf16 emb, padded
  short* x1h = (short*)alloc(((size_t)N + 256) * 64 * 2);    // bf16 x1
  short* Bt = (short*)alloc((size_t)12 * 4096 * 2);          // bf16 W_r^T
  short* w1h0 = (short*)alloc(4096 * 2);                     // layer-weight hi/lo
  short* w1l0 = (short*)alloc(4096 * 2);
  short* w2h0 = (short*)alloc(4096 * 2);
  short* w2l0 = (short*)alloc(4096 * 2);
  short* w1h1 = (short*)alloc(2048 * 2);
  short* w1l1 = (short*)alloc(2048 * 2);
  short* w2h1 = (short*)alloc(2048 * 2);
  short* w2l1 = (short*)alloc(2048 * 2);

  int n4 = N * 16;
  int nb_cvt = (n4 + 255) / 256;
  int nb1 = (E + BS1_TILE - 1) / BS1_TILE;  // bsort1 blocks (merged into prep)
  int nbg = (N + 255) / 256;                // GEMM blocks (256 nodes each)
  int nwg_lg = (E + 255) / 256;             // logits blocks (256 edges each)

  hipMemsetAsync(bcur, 0, 1024, stream);
  k_prep<<<nb1 + nb_cvt + 60, 256, 0, stream>>>(
      emb, emb_h, out, Wr, Bt, W10w, W20w, W11w, W21w,
      w1h0, w1l0, w2h0, w2l0, w1h1, w1l1, w2h1, w2l1,
      src, dst, et, bcur, stg, E, bsh, cap, nb1, nb_cvt, n4);
  k_projb2<<<nbg + nbuck, 256, 0, stream>>>(
      emb_h, Bt, proj, N, stg, bcur, row_ptr, csr2, nbg, bsh, cap, nbuck, E);
  k_logits<<<nwg_lg, 256, 0, stream>>>(proj, rel, csr2, E, N, nwg_lg);
  k_agg<<<(N + 3) / 4, 256, 0, stream>>>(emb_h, row_ptr, csr2, hn, N);
  k_upmfma<64, true><<<(N + 127) / 128, 256, 0, stream>>>(
      emb, hn, w1h0, w1l0, w2h0, w2l0, W10b, W20b, out, x1, x1h, N);
  k_agg<<<(N + 3) / 4, 256, 0, stream>>>(x1h, row_ptr, csr2, hn, N);
  k_upmfma<32, false><<<(N + 127) / 128, 256, 0, stream>>>(
      x1, hn, w1h1, w1l1, w2h1, w2l1, W11b, W21b, out, nullptr, nullptr, N);
}